// Round 1
// baseline (1327.579 us; speedup 1.0000x reference)
//
#include <hip/hip_runtime.h>
#include <math.h>

// ---------------------------------------------------------------------------
// AttentionModel: feat-> (tanh GEMM), 2x LSTM over axis0 (8 steps, batch 2048),
// score GEMM, banded softmax (width 129), banded PV, enhance GEMM (tanh),
// mask GEMM (sigmoid) * x.  All fp32 this round.
// ---------------------------------------------------------------------------

#define Bq 8
#define Tq 2048
#define Fq 257
#define Hq 256
#define Gq 1024          // 4*H
#define TH (Tq*Hq)       // 524288
#define WBAND 132        // padded band stride (129 used)

__device__ __forceinline__ float sigf(float x) { return 1.0f / (1.0f + __expf(-x)); }
__device__ __forceinline__ float tanh_f(float x) { return 1.0f - 2.0f / (__expf(2.0f * x) + 1.0f); }

// ------------------------------- generic NT GEMM ---------------------------
// C[m,n] = sum_k A[m,k] * W[n,k]   (A: M x K row-major lda, W: N x K row-major ldw)
constexpr int BM = 64, BN = 64, KT = 16, LDP = 68;  // LDP padding: 2-way-free banks, 16B aligned

__device__ __forceinline__ void gemm_seg(
    float (*a_s)[LDP], float (*w_s)[LDP],
    const float* __restrict__ A, int lda,
    const float* __restrict__ W, int ldw, int K,
    int m0, int n0, int M, int N, int tid, float acc[4][4])
{
    const int lk = tid & 15, lm = tid >> 4;   // loader mapping
    const int tx = tid & 15, ty = tid >> 4;   // compute mapping
    for (int k0 = 0; k0 < K; k0 += KT) {
        const int k = k0 + lk;
        const bool kv = (k < K);
#pragma unroll
        for (int r = 0; r < 4; ++r) {
            const int m = m0 + lm + 16 * r;
            a_s[lk][lm + 16 * r] = (kv && m < M) ? A[(size_t)m * lda + k] : 0.0f;
            const int n = n0 + lm + 16 * r;
            w_s[lk][lm + 16 * r] = (kv && n < N) ? W[(size_t)n * ldw + k] : 0.0f;
        }
        __syncthreads();
#pragma unroll
        for (int kk = 0; kk < KT; ++kk) {
            const float4 av = *(const float4*)&a_s[kk][4 * ty];
            const float4 wv = *(const float4*)&w_s[kk][4 * tx];
            const float aa[4] = {av.x, av.y, av.z, av.w};
            const float ww[4] = {wv.x, wv.y, wv.z, wv.w};
#pragma unroll
            for (int i = 0; i < 4; ++i)
#pragma unroll
                for (int j = 0; j < 4; ++j) acc[i][j] += aa[i] * ww[j];
        }
        __syncthreads();
    }
}

// ACT: 0 none, 1 tanh, 2 sigmoid. MULX: multiply by xm (elementwise) before store.
template <int ACT, bool MULX>
__global__ __launch_bounds__(256) void gemm_nt(
    const float* __restrict__ A1, int lda1, const float* __restrict__ W1, int ldw1, int K1,
    const float* __restrict__ A2, int lda2, const float* __restrict__ W2, int ldw2, int K2,
    const float* __restrict__ bias,
    const float* __restrict__ xm, int ldx,
    float* __restrict__ out, int ldo, int M, int N)
{
    __shared__ float a_s[KT][LDP];
    __shared__ float w_s[KT][LDP];
    const int m0 = blockIdx.y * BM, n0 = blockIdx.x * BN;
    const int tid = threadIdx.x;
    float acc[4][4] = {};
    gemm_seg(a_s, w_s, A1, lda1, W1, ldw1, K1, m0, n0, M, N, tid, acc);
    if (A2) gemm_seg(a_s, w_s, A2, lda2, W2, ldw2, K2, m0, n0, M, N, tid, acc);
    const int tx = tid & 15, ty = tid >> 4;
#pragma unroll
    for (int i = 0; i < 4; ++i) {
        const int m = m0 + 4 * ty + i;
        if (m >= M) continue;
#pragma unroll
        for (int j = 0; j < 4; ++j) {
            const int n = n0 + 4 * tx + j;
            if (n >= N) continue;
            float v = acc[i][j];
            if (bias) v += bias[n];
            if (ACT == 1) v = tanh_f(v);
            else if (ACT == 2) v = sigf(v);
            if (MULX) v *= xm[(size_t)m * ldx + n];
            out[(size_t)m * ldo + n] = v;
        }
    }
}

// ------------------------- LSTM gate GEMM (both LSTMs via z) ---------------
// gates = hx @ Wih^T + hprev @ Whh^T   (M=2048, N=1024, K=256+256)
__global__ __launch_bounds__(256) void lstm_gates(
    const float* __restrict__ hx,
    const float* __restrict__ hk_prev, const float* __restrict__ hq_prev,
    const float* __restrict__ kWih, const float* __restrict__ kWhh,
    const float* __restrict__ qWih, const float* __restrict__ qWhh,
    float* __restrict__ gk, float* __restrict__ gq)
{
    __shared__ float a_s[KT][LDP];
    __shared__ float w_s[KT][LDP];
    const int z = blockIdx.z;
    const float* A2 = z ? hq_prev : hk_prev;
    const float* W1 = z ? qWih : kWih;
    const float* W2 = z ? qWhh : kWhh;
    float* out = z ? gq : gk;
    const int m0 = blockIdx.y * BM, n0 = blockIdx.x * BN;
    const int tid = threadIdx.x;
    float acc[4][4] = {};
    gemm_seg(a_s, w_s, hx, Hq, W1, Hq, Hq, m0, n0, Tq, Gq, tid, acc);
    gemm_seg(a_s, w_s, A2, Hq, W2, Hq, Hq, m0, n0, Tq, Gq, tid, acc);
    const int tx = tid & 15, ty = tid >> 4;
#pragma unroll
    for (int i = 0; i < 4; ++i) {
        const int m = m0 + 4 * ty + i;
#pragma unroll
        for (int j = 0; j < 4; ++j) {
            const int n = n0 + 4 * tx + j;
            out[(size_t)m * Gq + n] = acc[i][j];
        }
    }
}

// ------------------------------- LSTM cell ---------------------------------
__global__ __launch_bounds__(256) void lstm_cell(
    const float* __restrict__ gk, const float* __restrict__ gq,
    const float* __restrict__ kbih, const float* __restrict__ kbhh,
    const float* __restrict__ qbih, const float* __restrict__ qbhh,
    float* __restrict__ ck, float* __restrict__ cq,
    float* __restrict__ hk_out, float* __restrict__ hq_out)
{
    const int z = blockIdx.y;
    const float* g = z ? gq : gk;
    const float* bih = z ? qbih : kbih;
    const float* bhh = z ? qbhh : kbhh;
    float* c = z ? cq : ck;
    float* h = z ? hq_out : hk_out;
    const int idx = blockIdx.x * 256 + threadIdx.x;  // 0 .. TH-1
    const int t = idx >> 8, j = idx & 255;
    const float* gr = g + (size_t)t * Gq;
    const float gi = gr[j] + bih[j] + bhh[j];
    const float gf = gr[256 + j] + bih[256 + j] + bhh[256 + j];
    const float gg = gr[512 + j] + bih[512 + j] + bhh[512 + j];
    const float go = gr[768 + j] + bih[768 + j] + bhh[768 + j];
    const float cn = sigf(gf) * c[idx] + sigf(gi) * tanh_f(gg);
    c[idx] = cn;
    h[idx] = sigf(go) * tanh_f(cn);
}

// --------------------------- banded softmax ---------------------------------
// one block per (b,t): s_o = q~[t] . k[t-128+o], softmax over valid o in [0,128]
__global__ __launch_bounds__(256) void band_softmax(
    const float* __restrict__ qs, const float* __restrict__ kb,
    float* __restrict__ wband, float* __restrict__ out1)
{
    const int b = blockIdx.y, t = blockIdx.x;
    const int tid = threadIdx.x;
    __shared__ float q_s[Hq];
    __shared__ float red[256];
    q_s[tid] = qs[((size_t)b * Tq + t) * Hq + tid];
    __syncthreads();

    const int o = tid;
    const int u = t - 128 + o;
    const bool act = (o <= 128) && (u >= 0);
    float s = -1e30f;
    if (act) {
        const float4* k4 = (const float4*)(kb + ((size_t)b * Tq + u) * Hq);
        const float4* q4 = (const float4*)q_s;
        float a = 0.0f;
#pragma unroll 4
        for (int kk = 0; kk < Hq / 4; ++kk) {
            const float4 kv = k4[kk];
            const float4 qv = q4[kk];
            a += qv.x * kv.x + qv.y * kv.y + qv.z * kv.z + qv.w * kv.w;
        }
        s = a;
    }
    red[tid] = s;
    __syncthreads();
    for (int st = 128; st > 0; st >>= 1) {
        if (tid < st) red[tid] = fmaxf(red[tid], red[tid + st]);
        __syncthreads();
    }
    const float mx = red[0];
    __syncthreads();
    const float e = act ? __expf(s - mx) : 0.0f;
    red[tid] = e;
    __syncthreads();
    for (int st = 128; st > 0; st >>= 1) {
        if (tid < st) red[tid] += red[tid + st];
        __syncthreads();
    }
    const float den = red[0] + 1e-10f;
    const float w = e / den;
    if (o <= 128) {
        wband[((size_t)b * Tq + t) * WBAND + o] = w;   // 0 for u<0 (e=0)
        if (u >= 0) out1[((size_t)b * Tq + t) * Tq + u] = w;
    }
}

// --------------------------- banded PV (c = w @ k) --------------------------
// block per (b, t-tile of 8); thread j accumulates c[t0+dt][j]
__global__ __launch_bounds__(256) void band_c(
    const float* __restrict__ wband, const float* __restrict__ kb,
    float* __restrict__ c_att)
{
    const int b = blockIdx.y;
    const int t0 = blockIdx.x * 8;
    const int tid = threadIdx.x;
    __shared__ float w_s[8][WBAND];
    const size_t base_row = (size_t)b * Tq + t0;
    for (int i = tid; i < 8 * WBAND; i += 256) {
        const int dt = i / WBAND, o = i - dt * WBAND;
        w_s[dt][o] = wband[(base_row + dt) * WBAND + o];
    }
    __syncthreads();
    float acc[8] = {};
    for (int du = 0; du < 136; ++du) {
        const int u = t0 - 128 + du;
        if (u < 0) continue;
        const float val = kb[((size_t)b * Tq + u) * Hq + tid];
#pragma unroll
        for (int dt = 0; dt < 8; ++dt) {
            const int o = du - dt;
            if (o >= 0 && o <= 128) acc[dt] += w_s[dt][o] * val;
        }
    }
#pragma unroll
    for (int dt = 0; dt < 8; ++dt)
        c_att[(base_row + dt) * Hq + tid] = acc[dt];
}

// ---------------------------------------------------------------------------
extern "C" void kernel_launch(void* const* d_in, const int* in_sizes, int n_in,
                              void* d_out, int out_size, void* d_ws, size_t ws_size,
                              hipStream_t stream)
{
    (void)in_sizes; (void)n_in; (void)out_size; (void)ws_size;
    const float* x        = (const float*)d_in[0];
    const float* feat_w   = (const float*)d_in[1];
    const float* feat_b   = (const float*)d_in[2];
    const float* k_Wih    = (const float*)d_in[3];
    const float* k_Whh    = (const float*)d_in[4];
    const float* k_bih    = (const float*)d_in[5];
    const float* k_bhh    = (const float*)d_in[6];
    const float* q_Wih    = (const float*)d_in[7];
    const float* q_Whh    = (const float*)d_in[8];
    const float* q_bih    = (const float*)d_in[9];
    const float* q_bhh    = (const float*)d_in[10];
    const float* score_w  = (const float*)d_in[11];
    const float* enhance_w= (const float*)d_in[12];
    const float* enhance_b= (const float*)d_in[13];
    const float* mask_w   = (const float*)d_in[14];
    const float* mask_b   = (const float*)d_in[15];

    float* out0 = (float*)d_out;                         // (8,2048,257)
    float* out1 = out0 + (size_t)Bq * Tq * Fq;           // (8,2048,2048)

    float* ws = (float*)d_ws;
    float* hfeat = ws;                       // 4,194,304  (also reused as q~ after LSTM)
    float* kbuf  = hfeat + (size_t)Bq * TH;  // 4,194,304  (also reused as out_h after PV)
    float* qbuf  = kbuf  + (size_t)Bq * TH;  // 4,194,304
    float* gbuf  = qbuf  + (size_t)Bq * TH;  // 4,194,304  (gates; reused as c_att)
    float* wband = gbuf  + (size_t)Bq * TH;  // 2,162,688
    float* cst   = wband + (size_t)Bq * Tq * WBAND;  // 1,048,576 (2 LSTM c states)
    float* zb    = cst   + (size_t)2 * TH;   // 524,288 zeros

    float* gk = gbuf;
    float* gq = gbuf + (size_t)TH * 4 / 2;   // gbuf + 2,097,152 (2048x1024 each)
    float* ck = cst;
    float* cq = cst + TH;

    // zero: c-states, zero-h buffer, dense w_ output region
    hipMemsetAsync(cst, 0, (size_t)2 * TH * sizeof(float), stream);
    hipMemsetAsync(zb, 0, (size_t)TH * sizeof(float), stream);
    hipMemsetAsync(out1, 0, (size_t)Bq * Tq * Tq * sizeof(float), stream);

    const int M = Bq * Tq;  // 16384

    // 1) feat: hfeat = tanh(x @ feat_w^T + feat_b)
    gemm_nt<1, false><<<dim3((Hq + BN - 1) / BN, M / BM), 256, 0, stream>>>(
        x, Fq, feat_w, Fq, Fq, nullptr, 0, nullptr, 0, 0,
        feat_b, nullptr, 0, hfeat, Hq, M, Hq);

    // 2) LSTM k & q: 8 steps over axis 0
    for (int b = 0; b < Bq; ++b) {
        const float* hx = hfeat + (size_t)b * TH;
        const float* pk = b ? kbuf + (size_t)(b - 1) * TH : zb;
        const float* pq = b ? qbuf + (size_t)(b - 1) * TH : zb;
        lstm_gates<<<dim3(Gq / BN, Tq / BM, 2), 256, 0, stream>>>(
            hx, pk, pq, k_Wih, k_Whh, q_Wih, q_Whh, gk, gq);
        lstm_cell<<<dim3(TH / 256, 2), 256, 0, stream>>>(
            gk, gq, k_bih, k_bhh, q_bih, q_bhh, ck, cq,
            kbuf + (size_t)b * TH, qbuf + (size_t)b * TH);
    }

    // 3) score: qs = q @ score_w^T   (qs reuses hfeat)
    float* qs = hfeat;
    gemm_nt<0, false><<<dim3(Hq / BN, M / BM), 256, 0, stream>>>(
        qbuf, Hq, score_w, Hq, Hq, nullptr, 0, nullptr, 0, 0,
        nullptr, nullptr, 0, qs, Hq, M, Hq);

    // 4) banded softmax -> wband + dense out1 rows
    band_softmax<<<dim3(Tq, Bq), 256, 0, stream>>>(qs, kbuf, wband, out1);

    // 5) banded PV: c_att = w @ k   (c_att reuses gbuf)
    float* c_att = gbuf;
    band_c<<<dim3(Tq / 8, Bq), 256, 0, stream>>>(wband, kbuf, c_att);

    // 6) enhance: out_h = tanh([c_att, q] @ enhance_w^T + enhance_b)  (reuses kbuf)
    float* out_h = kbuf;
    gemm_nt<1, false><<<dim3(Hq / BN, M / BM), 256, 0, stream>>>(
        c_att, Hq, enhance_w, 2 * Hq, Hq,
        qbuf, Hq, enhance_w + Hq, 2 * Hq, Hq,
        enhance_b, nullptr, 0, out_h, Hq, M, Hq);

    // 7) mask + final: out0 = x * sigmoid(out_h @ mask_w^T + mask_b)
    gemm_nt<2, true><<<dim3((Fq + BN - 1) / BN, M / BM), 256, 0, stream>>>(
        out_h, Hq, mask_w, Hq, Hq, nullptr, 0, nullptr, 0, 0,
        mask_b, x, Fq, out0, Fq, M, Fq);
}

// Round 2
// 645.495 us; speedup vs baseline: 2.0567x; 2.0567x over previous
//
#include <hip/hip_runtime.h>
#include <math.h>

// ---------------------------------------------------------------------------
// AttentionModel on MI355X. Round 2: all dense GEMMs -> bf16 MFMA (fp32 acc).
// feat GEMM, 2x LSTM over axis0 (8 steps, batch 2048), score GEMM,
// banded softmax (width 129, fp32, unchanged), banded PV, enhance GEMM,
// mask GEMM (sigmoid) * x.
// ---------------------------------------------------------------------------

#define Bq 8
#define Tq 2048
#define Fq 257
#define Hq 256
#define Gq 1024          // 4*H
#define TH (Tq*Hq)       // 524288
#define WBAND 132        // padded band stride (129 used)

typedef __bf16 bf16_t;
typedef __bf16 bf16x8 __attribute__((ext_vector_type(8)));
typedef float f32x4 __attribute__((ext_vector_type(4)));

__device__ __forceinline__ float sigf(float x) { return 1.0f / (1.0f + __expf(-x)); }
__device__ __forceinline__ float tanh_f(float x) { return 1.0f - 2.0f / (__expf(2.0f * x) + 1.0f); }

// ----------------------------- fp32 -> bf16 convert/pad ---------------------
// fills dst[r][col_off + c] for r in [0,rows), c in [0,cols); zero outside src
__global__ void f2bf(const float* __restrict__ src, bf16_t* __restrict__ dst,
                     int dst_ld, int col_off, int rows, int cols,
                     int src_rows, int src_cols)
{
    const int i = blockIdx.x * 256 + threadIdx.x;
    if (i >= rows * cols) return;
    const int r = i / cols, c = i - r * cols;
    const float v = (r < src_rows && c < src_cols) ? src[(size_t)r * src_cols + c] : 0.0f;
    dst[(size_t)r * dst_ld + col_off + c] = (bf16_t)v;
}

// ----------------------------- bf16 MFMA NT GEMM ----------------------------
// C[m,n] = sum_k A[m,k] * W[n,k];  A split in two K-segments (A1 K1 | A2 K2),
// W packed N x (K1+K2) row-major.  128x128 tile, 4 waves (2x2 of 64x64), BK=32.
template<int ACT, bool MULX, bool BF16OUT, bool F32OUT>
__device__ __forceinline__ void gemm_core(
    const bf16_t* __restrict__ A1, int lda1, int K1,
    const bf16_t* __restrict__ A2, int lda2, int K2,
    const bf16_t* __restrict__ W,
    const float* __restrict__ bias,
    const float* __restrict__ xm, int ldx,
    float* __restrict__ out, bf16_t* __restrict__ outbf, int ldo,
    int Nlog, int m0, int n0)
{
    __shared__ __align__(16) bf16_t As[128 * 32];
    __shared__ __align__(16) bf16_t Ws[128 * 32];
    const int tid = threadIdx.x;
    const int lane = tid & 63;
    const int wave = tid >> 6;
    const int wr = wave >> 1, wc = wave & 1;
    const int fr = lane & 15;            // fragment row (A) / col (B) / col (D)
    const int fo = (lane >> 4) * 8;      // k offset within 32
    const int srow = tid >> 2;           // staging row (chunk0), 0..63
    const int scol = (tid & 3) * 8;      // staging element col within 32

    f32x4 acc[4][4] = {};

    const int K = K1 + K2;
    const int ldw = K;
    for (int k0 = 0; k0 < K; k0 += 32) {
        const bf16_t* Aseg; int kk, lda;
        if (k0 < K1) { Aseg = A1; kk = k0;      lda = lda1; }
        else         { Aseg = A2; kk = k0 - K1; lda = lda2; }
        // issue global loads early (overlap with prior compute drain)
        const uint4 a0 = *(const uint4*)(Aseg + (size_t)(m0 + srow)      * lda + kk + scol);
        const uint4 a1 = *(const uint4*)(Aseg + (size_t)(m0 + srow + 64) * lda + kk + scol);
        const uint4 w0 = *(const uint4*)(W    + (size_t)(n0 + srow)      * ldw + k0 + scol);
        const uint4 w1 = *(const uint4*)(W    + (size_t)(n0 + srow + 64) * ldw + k0 + scol);
        __syncthreads();                 // prior LDS reads done before overwrite
        *(uint4*)&As[srow * 32 + scol]        = a0;
        *(uint4*)&As[(srow + 64) * 32 + scol] = a1;
        *(uint4*)&Ws[srow * 32 + scol]        = w0;
        *(uint4*)&Ws[(srow + 64) * 32 + scol] = w1;
        __syncthreads();
        bf16x8 af[4], bfr[4];
#pragma unroll
        for (int i = 0; i < 4; ++i) af[i]  = *(const bf16x8*)&As[(wr * 64 + i * 16 + fr) * 32 + fo];
#pragma unroll
        for (int j = 0; j < 4; ++j) bfr[j] = *(const bf16x8*)&Ws[(wc * 64 + j * 16 + fr) * 32 + fo];
#pragma unroll
        for (int i = 0; i < 4; ++i)
#pragma unroll
            for (int j = 0; j < 4; ++j)
                acc[i][j] = __builtin_amdgcn_mfma_f32_16x16x32_bf16(af[i], bfr[j], acc[i][j], 0, 0, 0);
    }

    // epilogue: D mapping col = lane&15, row = (lane>>4)*4 + reg
    const int rbase = (lane >> 4) * 4;
#pragma unroll
    for (int i = 0; i < 4; ++i) {
#pragma unroll
        for (int j = 0; j < 4; ++j) {
            const int n = n0 + wc * 64 + j * 16 + fr;
            if (n >= Nlog) continue;
            const float bv = bias ? bias[n] : 0.0f;
            const int m = m0 + wr * 64 + i * 16 + rbase;
#pragma unroll
            for (int r = 0; r < 4; ++r) {
                float v = acc[i][j][r] + bv;
                if (ACT == 1) v = tanh_f(v);
                else if (ACT == 2) v = sigf(v);
                if (MULX) v *= xm[(size_t)(m + r) * ldx + n];
                if (F32OUT) out[(size_t)(m + r) * ldo + n] = v;
                if (BF16OUT) outbf[(size_t)(m + r) * ldo + n] = (bf16_t)v;
            }
        }
    }
}

template<int ACT, bool MULX, bool BF16OUT, bool F32OUT>
__global__ __launch_bounds__(256) void gemm_mfma(
    const bf16_t* A1, int lda1, int K1, const bf16_t* A2, int lda2, int K2,
    const bf16_t* W, const float* bias, const float* xm, int ldx,
    float* out, bf16_t* outbf, int ldo, int Nlog)
{
    gemm_core<ACT, MULX, BF16OUT, F32OUT>(A1, lda1, K1, A2, lda2, K2, W, bias, xm, ldx,
                                          out, outbf, ldo, Nlog,
                                          blockIdx.y * 128, blockIdx.x * 128);
}

// gates = hx @ Wih^T + hprev @ Whh^T  (both LSTMs via blockIdx.z)
__global__ __launch_bounds__(256) void lstm_gates_mfma(
    const bf16_t* hx, const bf16_t* pk, const bf16_t* pq,
    const bf16_t* Wk, const bf16_t* Wq, float* gk, float* gq)
{
    const int z = blockIdx.z;
    gemm_core<0, false, false, true>(hx, Hq, Hq, z ? pq : pk, Hq, Hq, z ? Wq : Wk,
                                     nullptr, nullptr, 0, z ? gq : gk, nullptr, Gq, 1 << 30,
                                     blockIdx.y * 128, blockIdx.x * 128);
}

// ------------------------------- LSTM cell ---------------------------------
__global__ __launch_bounds__(256) void lstm_cell(
    const float* __restrict__ gk, const float* __restrict__ gq,
    const float* __restrict__ kbih, const float* __restrict__ kbhh,
    const float* __restrict__ qbih, const float* __restrict__ qbhh,
    float* __restrict__ ck, float* __restrict__ cq,
    float* __restrict__ hkf, bf16_t* __restrict__ hkb, bf16_t* __restrict__ hqb)
{
    const int z = blockIdx.y;
    const float* g   = z ? gq : gk;
    const float* bih = z ? qbih : kbih;
    const float* bhh = z ? qbhh : kbhh;
    float* c = z ? cq : ck;
    const int idx = blockIdx.x * 256 + threadIdx.x;   // 0 .. TH-1
    const int t = idx >> 8, j = idx & 255;
    const float* gr = g + (size_t)t * Gq;
    const float gi = gr[j]       + bih[j]       + bhh[j];
    const float gf = gr[256 + j] + bih[256 + j] + bhh[256 + j];
    const float gg = gr[512 + j] + bih[512 + j] + bhh[512 + j];
    const float go = gr[768 + j] + bih[768 + j] + bhh[768 + j];
    const float cn = sigf(gf) * c[idx] + sigf(gi) * tanh_f(gg);
    c[idx] = cn;
    const float h = sigf(go) * tanh_f(cn);
    if (z) {
        hqb[idx] = (bf16_t)h;
    } else {
        hkf[idx] = h;
        hkb[idx] = (bf16_t)h;
    }
}

// --------------------------- banded softmax (unchanged) ---------------------
__global__ __launch_bounds__(256) void band_softmax(
    const float* __restrict__ qs, const float* __restrict__ kb,
    float* __restrict__ wband, float* __restrict__ out1)
{
    const int b = blockIdx.y, t = blockIdx.x;
    const int tid = threadIdx.x;
    __shared__ float q_s[Hq];
    __shared__ float red[256];
    q_s[tid] = qs[((size_t)b * Tq + t) * Hq + tid];
    __syncthreads();

    const int o = tid;
    const int u = t - 128 + o;
    const bool act = (o <= 128) && (u >= 0);
    float s = -1e30f;
    if (act) {
        const float4* k4 = (const float4*)(kb + ((size_t)b * Tq + u) * Hq);
        const float4* q4 = (const float4*)q_s;
        float a = 0.0f;
#pragma unroll 4
        for (int kk = 0; kk < Hq / 4; ++kk) {
            const float4 kv = k4[kk];
            const float4 qv = q4[kk];
            a += qv.x * kv.x + qv.y * kv.y + qv.z * kv.z + qv.w * kv.w;
        }
        s = a;
    }
    red[tid] = s;
    __syncthreads();
    for (int st = 128; st > 0; st >>= 1) {
        if (tid < st) red[tid] = fmaxf(red[tid], red[tid + st]);
        __syncthreads();
    }
    const float mx = red[0];
    __syncthreads();
    const float e = act ? __expf(s - mx) : 0.0f;
    red[tid] = e;
    __syncthreads();
    for (int st = 128; st > 0; st >>= 1) {
        if (tid < st) red[tid] += red[tid + st];
        __syncthreads();
    }
    const float den = red[0] + 1e-10f;
    const float w = e / den;
    if (o <= 128) {
        wband[((size_t)b * Tq + t) * WBAND + o] = w;   // 0 for u<0 (e=0)
        if (u >= 0) out1[((size_t)b * Tq + t) * Tq + u] = w;
    }
}

// --------------------------- banded PV (c = w @ k) --------------------------
__global__ __launch_bounds__(256) void band_c(
    const float* __restrict__ wband, const float* __restrict__ kb,
    bf16_t* __restrict__ c_att)
{
    const int b = blockIdx.y;
    const int t0 = blockIdx.x * 8;
    const int tid = threadIdx.x;
    __shared__ float w_s[8][WBAND];
    const size_t base_row = (size_t)b * Tq + t0;
    for (int i = tid; i < 8 * WBAND; i += 256) {
        const int dt = i / WBAND, o = i - dt * WBAND;
        w_s[dt][o] = wband[(base_row + dt) * WBAND + o];
    }
    __syncthreads();
    float acc[8] = {};
    for (int du = 0; du < 136; ++du) {
        const int u = t0 - 128 + du;
        if (u < 0) continue;
        const float val = kb[((size_t)b * Tq + u) * Hq + tid];
#pragma unroll
        for (int dt = 0; dt < 8; ++dt) {
            const int o = du - dt;
            if (o >= 0 && o <= 128) acc[dt] += w_s[dt][o] * val;
        }
    }
#pragma unroll
    for (int dt = 0; dt < 8; ++dt)
        c_att[(base_row + dt) * Hq + tid] = (bf16_t)acc[dt];
}

// ---------------------------------------------------------------------------
extern "C" void kernel_launch(void* const* d_in, const int* in_sizes, int n_in,
                              void* d_out, int out_size, void* d_ws, size_t ws_size,
                              hipStream_t stream)
{
    (void)in_sizes; (void)n_in; (void)out_size; (void)ws_size;
    const float* x        = (const float*)d_in[0];
    const float* feat_w   = (const float*)d_in[1];
    const float* feat_b   = (const float*)d_in[2];
    const float* k_Wih    = (const float*)d_in[3];
    const float* k_Whh    = (const float*)d_in[4];
    const float* k_bih    = (const float*)d_in[5];
    const float* k_bhh    = (const float*)d_in[6];
    const float* q_Wih    = (const float*)d_in[7];
    const float* q_Whh    = (const float*)d_in[8];
    const float* q_bih    = (const float*)d_in[9];
    const float* q_bhh    = (const float*)d_in[10];
    const float* score_w  = (const float*)d_in[11];
    const float* enhance_w= (const float*)d_in[12];
    const float* enhance_b= (const float*)d_in[13];
    const float* mask_w   = (const float*)d_in[14];
    const float* mask_b   = (const float*)d_in[15];

    float* out0 = (float*)d_out;                         // (8,2048,257)
    float* out1 = out0 + (size_t)Bq * Tq * Fq;           // (8,2048,2048)

    const int M = Bq * Tq;  // 16384

    // ---- workspace layout (fp32 first, then bf16) ----
    float* ws = (float*)d_ws;
    float* kbuf  = ws;                                   // 4,194,304 f32 (k states, fp32 for band kernels)
    float* gbuf  = kbuf + (size_t)Bq * TH;               // 4,194,304 f32 (gates; reused as qs)
    float* wband = gbuf + (size_t)Bq * TH;               // 2,162,688 f32
    float* cst   = wband + (size_t)Bq * Tq * WBAND;      // 1,048,576 f32 (c states)
    bf16_t* bws  = (bf16_t*)(cst + (size_t)2 * TH);      // bf16 region (16B-aligned)

    bf16_t* xbf     = bws;                               // 16384x288 = 4,718,592 (reused as c_att)
    bf16_t* hfeatbf = xbf + (size_t)M * 288;             // 16384x256 = 4,194,304 (reused as out_h)
    bf16_t* hkbf    = hfeatbf + (size_t)M * Hq;          // 2xTH ping-pong = 1,048,576
    bf16_t* hqbf    = hkbf + (size_t)2 * TH;             // 8xTH = 4,194,304
    bf16_t* zbf     = hqbf + (size_t)Bq * TH;            // 524,288 zeros
    bf16_t* featw   = zbf + (size_t)TH;                  // 256x288 = 73,728
    bf16_t* Wk      = featw + 256 * 288;                 // 1024x512 = 524,288
    bf16_t* Wq      = Wk + 1024 * 512;                   // 524,288
    bf16_t* scw     = Wq + 1024 * 512;                   // 256x256 = 65,536
    bf16_t* enw     = scw + 256 * 256;                   // 256x512 = 131,072
    bf16_t* mkw     = enw + 256 * 512;                   // 384x256 = 98,304

    float* gk = gbuf;
    float* gq = gbuf + (size_t)Tq * Gq;                  // gbuf + 2,097,152
    float* ck = cst;
    float* cq = cst + TH;

    hipMemsetAsync(cst, 0, (size_t)2 * TH * sizeof(float), stream);
    hipMemsetAsync(zbf, 0, (size_t)TH * sizeof(bf16_t), stream);
    hipMemsetAsync(out1, 0, (size_t)Bq * Tq * Tq * sizeof(float), stream);

    // ---- convert inputs/weights to bf16 (padded where needed) ----
    auto cvt = [&](const float* src, bf16_t* dst, int dld, int coff,
                   int rows, int cols, int srows, int scols) {
        f2bf<<<(rows * cols + 255) / 256, 256, 0, stream>>>(src, dst, dld, coff, rows, cols, srows, scols);
    };
    cvt(x,        xbf,   288, 0,   M, 288,     M, Fq);     // zero-padded K 257->288
    cvt(feat_w,   featw, 288, 0, 256, 288,   256, Fq);
    cvt(k_Wih,    Wk,    512, 0,   Gq, Hq,    Gq, Hq);
    cvt(k_Whh,    Wk,    512, Hq,  Gq, Hq,    Gq, Hq);
    cvt(q_Wih,    Wq,    512, 0,   Gq, Hq,    Gq, Hq);
    cvt(q_Whh,    Wq,    512, Hq,  Gq, Hq,    Gq, Hq);
    cvt(score_w,  scw,   256, 0, 256, 256,   256, 256);
    cvt(enhance_w,enw,   512, 0, 256, 512,   256, 512);
    cvt(mask_w,   mkw,   256, 0, 384, 256,    Fq, 256);    // zero-padded N 257->384

    // 1) feat: hfeatbf = tanh(x @ feat_w^T + feat_b)   [bf16 out only]
    gemm_mfma<1, false, true, false><<<dim3(2, M / 128), 256, 0, stream>>>(
        xbf, 288, 288, nullptr, 0, 0, featw, feat_b, nullptr, 0,
        nullptr, hfeatbf, Hq, 1 << 30);

    // 2) LSTM k & q: 8 steps over axis 0
    for (int b = 0; b < Bq; ++b) {
        const bf16_t* pk = b ? hkbf + (size_t)((b - 1) & 1) * TH : zbf;
        const bf16_t* pq = b ? hqbf + (size_t)(b - 1) * TH : zbf;
        lstm_gates_mfma<<<dim3(Gq / 128, Tq / 128, 2), 256, 0, stream>>>(
            hfeatbf + (size_t)b * TH, pk, pq, Wk, Wq, gk, gq);
        lstm_cell<<<dim3(TH / 256, 2), 256, 0, stream>>>(
            gk, gq, k_bih, k_bhh, q_bih, q_bhh, ck, cq,
            kbuf + (size_t)b * TH, hkbf + (size_t)(b & 1) * TH, hqbf + (size_t)b * TH);
    }

    // 3) score: qs = q @ score_w^T  (fp32 out, reuses gbuf)
    float* qs = gbuf;
    gemm_mfma<0, false, false, true><<<dim3(2, M / 128), 256, 0, stream>>>(
        hqbf, Hq, Hq, nullptr, 0, 0, scw, nullptr, nullptr, 0,
        qs, nullptr, Hq, 1 << 30);

    // 4) banded softmax -> wband + dense out1 rows
    band_softmax<<<dim3(Tq, Bq), 256, 0, stream>>>(qs, kbuf, wband, out1);

    // 5) banded PV: c_att = w @ k  (bf16 out, reuses xbf)
    bf16_t* c_att = xbf;
    band_c<<<dim3(Tq / 8, Bq), 256, 0, stream>>>(wband, kbuf, c_att);

    // 6) enhance: out_h = tanh([c, q] @ enhance_w^T + b)  (bf16 out, reuses hfeatbf)
    bf16_t* outh = hfeatbf;
    gemm_mfma<1, false, true, false><<<dim3(2, M / 128), 256, 0, stream>>>(
        c_att, Hq, Hq, hqbf, Hq, Hq, enw, enhance_b, nullptr, 0,
        nullptr, outh, Hq, 1 << 30);

    // 7) mask + final: out0 = x * sigmoid(out_h @ mask_w^T + mask_b)
    gemm_mfma<2, true, false, true><<<dim3(3, M / 128), 256, 0, stream>>>(
        outh, Hq, Hq, nullptr, 0, 0, mkw, mask_b, x, Fq,
        out0, nullptr, Fq, Fq);
}

// Round 3
// 322.097 us; speedup vs baseline: 4.1217x; 2.0040x over previous
//
#include <hip/hip_runtime.h>
#include <math.h>

// ---------------------------------------------------------------------------
// AttentionModel on MI355X. Round 3: fused MFMA band-attention kernel
// (replaces gather-bound band_softmax + band_c). All GEMMs bf16 MFMA.
// ---------------------------------------------------------------------------

#define Bq 8
#define Tq 2048
#define Fq 257
#define Hq 256
#define Gq 1024          // 4*H
#define TH (Tq*Hq)       // 524288
#define KW 192           // k-window rows per 64-row t-tile
#define PLD 40           // P row stride (bf16), mult of 8, odd dword stride
#define KTLD 40          // KT row stride (bf16)

typedef __bf16 bf16_t;
typedef __bf16 bf16x8 __attribute__((ext_vector_type(8)));
typedef float f32x4 __attribute__((ext_vector_type(4)));

__device__ __forceinline__ float sigf(float x) { return 1.0f / (1.0f + __expf(-x)); }
__device__ __forceinline__ float tanh_f(float x) { return 1.0f - 2.0f / (__expf(2.0f * x) + 1.0f); }

// ----------------------------- fp32 -> bf16 convert/pad ---------------------
__global__ void f2bf(const float* __restrict__ src, bf16_t* __restrict__ dst,
                     int dst_ld, int col_off, int rows, int cols,
                     int src_rows, int src_cols)
{
    const int i = blockIdx.x * 256 + threadIdx.x;
    if (i >= rows * cols) return;
    const int r = i / cols, c = i - r * cols;
    const float v = (r < src_rows && c < src_cols) ? src[(size_t)r * src_cols + c] : 0.0f;
    dst[(size_t)r * dst_ld + col_off + c] = (bf16_t)v;
}

// ----------------------------- bf16 MFMA NT GEMM ----------------------------
// C[m,n] = sum_k A[m,k] * W[n,k]; A split in two K-segments; W packed N x K.
// 128x128 tile, 4 waves (2x2 of 64x64), BK=32.
template<int ACT, bool MULX, bool BF16OUT, bool F32OUT>
__device__ __forceinline__ void gemm_core(
    const bf16_t* __restrict__ A1, int lda1, int K1,
    const bf16_t* __restrict__ A2, int lda2, int K2,
    const bf16_t* __restrict__ W,
    const float* __restrict__ bias,
    const float* __restrict__ xm, int ldx,
    float* __restrict__ out, bf16_t* __restrict__ outbf, int ldo,
    int Nlog, int m0, int n0)
{
    __shared__ __align__(16) bf16_t As[128 * 32];
    __shared__ __align__(16) bf16_t Ws[128 * 32];
    const int tid = threadIdx.x;
    const int lane = tid & 63;
    const int wave = tid >> 6;
    const int wr = wave >> 1, wc = wave & 1;
    const int fr = lane & 15;
    const int fo = (lane >> 4) * 8;
    const int srow = tid >> 2;
    const int scol = (tid & 3) * 8;

    f32x4 acc[4][4] = {};

    const int K = K1 + K2;
    const int ldw = K;
    for (int k0 = 0; k0 < K; k0 += 32) {
        const bf16_t* Aseg; int kk, lda;
        if (k0 < K1) { Aseg = A1; kk = k0;      lda = lda1; }
        else         { Aseg = A2; kk = k0 - K1; lda = lda2; }
        const uint4 a0 = *(const uint4*)(Aseg + (size_t)(m0 + srow)      * lda + kk + scol);
        const uint4 a1 = *(const uint4*)(Aseg + (size_t)(m0 + srow + 64) * lda + kk + scol);
        const uint4 w0 = *(const uint4*)(W    + (size_t)(n0 + srow)      * ldw + k0 + scol);
        const uint4 w1 = *(const uint4*)(W    + (size_t)(n0 + srow + 64) * ldw + k0 + scol);
        __syncthreads();
        *(uint4*)&As[srow * 32 + scol]        = a0;
        *(uint4*)&As[(srow + 64) * 32 + scol] = a1;
        *(uint4*)&Ws[srow * 32 + scol]        = w0;
        *(uint4*)&Ws[(srow + 64) * 32 + scol] = w1;
        __syncthreads();
        bf16x8 af[4], bfr[4];
#pragma unroll
        for (int i = 0; i < 4; ++i) af[i]  = *(const bf16x8*)&As[(wr * 64 + i * 16 + fr) * 32 + fo];
#pragma unroll
        for (int j = 0; j < 4; ++j) bfr[j] = *(const bf16x8*)&Ws[(wc * 64 + j * 16 + fr) * 32 + fo];
#pragma unroll
        for (int i = 0; i < 4; ++i)
#pragma unroll
            for (int j = 0; j < 4; ++j)
                acc[i][j] = __builtin_amdgcn_mfma_f32_16x16x32_bf16(af[i], bfr[j], acc[i][j], 0, 0, 0);
    }

    const int rbase = (lane >> 4) * 4;
#pragma unroll
    for (int i = 0; i < 4; ++i) {
#pragma unroll
        for (int j = 0; j < 4; ++j) {
            const int n = n0 + wc * 64 + j * 16 + fr;
            if (n >= Nlog) continue;
            const float bv = bias ? bias[n] : 0.0f;
            const int m = m0 + wr * 64 + i * 16 + rbase;
#pragma unroll
            for (int r = 0; r < 4; ++r) {
                float v = acc[i][j][r] + bv;
                if (ACT == 1) v = tanh_f(v);
                else if (ACT == 2) v = sigf(v);
                if (MULX) v *= xm[(size_t)(m + r) * ldx + n];
                if (F32OUT) out[(size_t)(m + r) * ldo + n] = v;
                if (BF16OUT) outbf[(size_t)(m + r) * ldo + n] = (bf16_t)v;
            }
        }
    }
}

template<int ACT, bool MULX, bool BF16OUT, bool F32OUT>
__global__ __launch_bounds__(256) void gemm_mfma(
    const bf16_t* A1, int lda1, int K1, const bf16_t* A2, int lda2, int K2,
    const bf16_t* W, const float* bias, const float* xm, int ldx,
    float* out, bf16_t* outbf, int ldo, int Nlog)
{
    gemm_core<ACT, MULX, BF16OUT, F32OUT>(A1, lda1, K1, A2, lda2, K2, W, bias, xm, ldx,
                                          out, outbf, ldo, Nlog,
                                          blockIdx.y * 128, blockIdx.x * 128);
}

// gates = hx @ Wih^T + hprev @ Whh^T  (both LSTMs via blockIdx.z)
__global__ __launch_bounds__(256) void lstm_gates_mfma(
    const bf16_t* hx, const bf16_t* pk, const bf16_t* pq,
    const bf16_t* Wk, const bf16_t* Wq, float* gk, float* gq)
{
    const int z = blockIdx.z;
    gemm_core<0, false, false, true>(hx, Hq, Hq, z ? pq : pk, Hq, Hq, z ? Wq : Wk,
                                     nullptr, nullptr, 0, z ? gq : gk, nullptr, Gq, 1 << 30,
                                     blockIdx.y * 128, blockIdx.x * 128);
}

// ------------------------------- LSTM cell ---------------------------------
__global__ __launch_bounds__(256) void lstm_cell(
    const float* __restrict__ gk, const float* __restrict__ gq,
    const float* __restrict__ kbih, const float* __restrict__ kbhh,
    const float* __restrict__ qbih, const float* __restrict__ qbhh,
    float* __restrict__ ck, float* __restrict__ cq,
    bf16_t* __restrict__ hkb, bf16_t* __restrict__ hqb)
{
    const int z = blockIdx.y;
    const float* g   = z ? gq : gk;
    const float* bih = z ? qbih : kbih;
    const float* bhh = z ? qbhh : kbhh;
    float* c = z ? cq : ck;
    const int idx = blockIdx.x * 256 + threadIdx.x;
    const int t = idx >> 8, j = idx & 255;
    const float* gr = g + (size_t)t * Gq;
    const float gi = gr[j]       + bih[j]       + bhh[j];
    const float gf = gr[256 + j] + bih[256 + j] + bhh[256 + j];
    const float gg = gr[512 + j] + bih[512 + j] + bhh[512 + j];
    const float go = gr[768 + j] + bih[768 + j] + bhh[768 + j];
    const float cn = sigf(gf) * c[idx] + sigf(gi) * tanh_f(gg);
    c[idx] = cn;
    const float h = sigf(go) * tanh_f(cn);
    (z ? hqb : hkb)[idx] = (bf16_t)h;
}

// ----------------------- fused banded attention -----------------------------
// Per block: batch b, 64 t-rows. Stage K window (192x256 bf16) in LDS,
// QK^T via MFMA (wave w owns rows 16w..16w+15 x 192 cols), exact in-register
// band softmax, w -> out1 (coalesced) + P (bf16, LDS), PV via MFMA with
// per-32-j-chunk LDS transpose of K.
__global__ __launch_bounds__(256) void band_fused(
    const bf16_t* __restrict__ qsbf, const bf16_t* __restrict__ kbf,
    float* __restrict__ out1, bf16_t* __restrict__ c_att)
{
    __shared__ __align__(16) bf16_t Ks[8 * KW * 32];     // 98304 B, [h/32][j][32]
    __shared__ __align__(16) bf16_t P[6 * 64 * PLD];     // 30720 B, [j/32][i][PLD]
    __shared__ __align__(16) bf16_t KT[256 * KTLD];      // 20480 B, [h][KTLD]

    const int b = blockIdx.y;
    const int t0 = blockIdx.x * 64;
    const int u0 = t0 - 128;
    const int tid = threadIdx.x, lane = tid & 63, w = tid >> 6;
    const int fr = lane & 15, rg = lane >> 4, fo = rg * 8;
    const size_t kbase = (size_t)b * Tq;

    // ---- stage K window rows u0 .. u0+191 (coalesced; zeros for u<0) ----
#pragma unroll
    for (int it = 0; it < 24; ++it) {
        const int idx = it * 256 + tid;
        const int n  = idx >> 5;          // window row 0..191
        const int c8 = (idx & 31) * 8;    // col start
        uint4 v = {0, 0, 0, 0};
        const int u = u0 + n;
        if (u >= 0) v = *(const uint4*)(kbf + (kbase + u) * (size_t)Hq + c8);
        *(uint4*)&Ks[((c8 >> 5) * KW + n) * 32 + (c8 & 31)] = v;
    }
    __syncthreads();

    // ---- QK^T: S[i][j], i = 16w + rg*4 + r, j = 16jf + fr ----
    f32x4 acc[12] = {};
    const bf16_t* qrow = qsbf + (kbase + t0 + 16 * w + fr) * (size_t)Hq;
#pragma unroll
    for (int ks = 0; ks < 8; ++ks) {
        const bf16x8 aq = *(const bf16x8*)(qrow + ks * 32 + fo);
#pragma unroll
        for (int jf = 0; jf < 12; ++jf) {
            const bf16x8 bk = *(const bf16x8*)&Ks[(ks * KW + jf * 16 + fr) * 32 + fo];
            acc[jf] = __builtin_amdgcn_mfma_f32_16x16x32_bf16(aq, bk, acc[jf], 0, 0, 0);
        }
    }

    // ---- band softmax (exact; valid j in [max(i, 128-t0), i+128]) ----
    const int jmin = (128 - t0) > 0 ? (128 - t0) : 0;
    float mx[4] = {-3e38f, -3e38f, -3e38f, -3e38f};
#pragma unroll
    for (int jf = 0; jf < 12; ++jf)
#pragma unroll
        for (int r = 0; r < 4; ++r) {
            const int i = 16 * w + rg * 4 + r;
            const int j = jf * 16 + fr;
            if (j >= i && j <= i + 128 && j >= jmin)
                mx[r] = fmaxf(mx[r], acc[jf][r]);
        }
#pragma unroll
    for (int d = 1; d < 16; d <<= 1)
#pragma unroll
        for (int r = 0; r < 4; ++r) mx[r] = fmaxf(mx[r], __shfl_xor(mx[r], d));

    float ex[12][4];
    float sm[4] = {0.0f, 0.0f, 0.0f, 0.0f};
#pragma unroll
    for (int jf = 0; jf < 12; ++jf)
#pragma unroll
        for (int r = 0; r < 4; ++r) {
            const int i = 16 * w + rg * 4 + r;
            const int j = jf * 16 + fr;
            const bool v = (j >= i && j <= i + 128 && j >= jmin);
            const float e = v ? __expf(acc[jf][r] - mx[r]) : 0.0f;
            ex[jf][r] = e;
            sm[r] += e;
        }
#pragma unroll
    for (int d = 1; d < 16; d <<= 1)
#pragma unroll
        for (int r = 0; r < 4; ++r) sm[r] += __shfl_xor(sm[r], d);
    float inv[4];
#pragma unroll
    for (int r = 0; r < 4; ++r) inv[r] = 1.0f / (sm[r] + 1e-10f);

    // ---- write w -> out1 (dense rows, coalesced 16-lane runs) + P (LDS) ----
#pragma unroll
    for (int jf = 0; jf < 12; ++jf)
#pragma unroll
        for (int r = 0; r < 4; ++r) {
            const int i = 16 * w + rg * 4 + r;
            const int j = jf * 16 + fr;
            const float wv = ex[jf][r] * inv[r];
            if (u0 + j >= 0)
                out1[(kbase + t0 + i) * (size_t)Tq + (u0 + j)] = wv;
            P[((j >> 5) * 64 + i) * PLD + (j & 31)] = (bf16_t)wv;
        }

    // ---- PV: C[i][h] = sum_j P[i][j] K[j][h], per-32-j chunk with transpose ----
    f32x4 cacc[16] = {};
    for (int jc = 0; jc < 6; ++jc) {
        __syncthreads();   // P visible (jc=0); prior KT reads done (jc>0)
#pragma unroll
        for (int it = 0; it < 4; ++it) {
            const int idx = it * 256 + tid;
            const int jl = idx >> 5;          // 0..31 within chunk
            const int hc = (idx & 31) * 8;    // h start
            const bf16x8 kv = *(const bf16x8*)&Ks[((hc >> 5) * KW + jc * 32 + jl) * 32 + (hc & 31)];
#pragma unroll
            for (int e = 0; e < 8; ++e) KT[(hc + e) * KTLD + jl] = kv[e];
        }
        __syncthreads();
        const bf16x8 pa = *(const bf16x8*)&P[(jc * 64 + 16 * w + fr) * PLD + fo];
#pragma unroll
        for (int hf = 0; hf < 16; ++hf) {
            const bf16x8 bk = *(const bf16x8*)&KT[(hf * 16 + fr) * KTLD + fo];
            cacc[hf] = __builtin_amdgcn_mfma_f32_16x16x32_bf16(pa, bk, cacc[hf], 0, 0, 0);
        }
    }

    // ---- store c_att bf16 ----
#pragma unroll
    for (int hf = 0; hf < 16; ++hf)
#pragma unroll
        for (int r = 0; r < 4; ++r) {
            const int i = 16 * w + rg * 4 + r;
            c_att[(kbase + t0 + i) * (size_t)Hq + hf * 16 + fr] = (bf16_t)cacc[hf][r];
        }
}

// ---------------------------------------------------------------------------
extern "C" void kernel_launch(void* const* d_in, const int* in_sizes, int n_in,
                              void* d_out, int out_size, void* d_ws, size_t ws_size,
                              hipStream_t stream)
{
    (void)in_sizes; (void)n_in; (void)out_size; (void)ws_size;
    const float* x        = (const float*)d_in[0];
    const float* feat_w   = (const float*)d_in[1];
    const float* feat_b   = (const float*)d_in[2];
    const float* k_Wih    = (const float*)d_in[3];
    const float* k_Whh    = (const float*)d_in[4];
    const float* k_bih    = (const float*)d_in[5];
    const float* k_bhh    = (const float*)d_in[6];
    const float* q_Wih    = (const float*)d_in[7];
    const float* q_Whh    = (const float*)d_in[8];
    const float* q_bih    = (const float*)d_in[9];
    const float* q_bhh    = (const float*)d_in[10];
    const float* score_w  = (const float*)d_in[11];
    const float* enhance_w= (const float*)d_in[12];
    const float* enhance_b= (const float*)d_in[13];
    const float* mask_w   = (const float*)d_in[14];
    const float* mask_b   = (const float*)d_in[15];

    float* out0 = (float*)d_out;                         // (8,2048,257)
    float* out1 = out0 + (size_t)Bq * Tq * Fq;           // (8,2048,2048)

    const int M = Bq * Tq;  // 16384

    // ---- workspace layout ----
    float* ws = (float*)d_ws;
    float* gbuf = ws;                                    // 4,194,304 f32 (gates; reused as c_att bf16)
    float* cst  = gbuf + (size_t)2 * Tq * Gq / 1;        // careful: gates = 2 x (2048x1024)
    // gbuf holds gk (2048x1024) + gq (2048x1024) = 4,194,304 floats total
    cst = gbuf + (size_t)2 * Tq * Gq;                    // 2*2048*1024 = 4,194,304
    bf16_t* bws = (bf16_t*)(cst + (size_t)2 * TH);

    bf16_t* xbf     = bws;                               // M*288 (reused as qsbf)
    bf16_t* hfeatbf = xbf + (size_t)M * 288;             // M*256 (reused as out_h)
    bf16_t* hkbf    = hfeatbf + (size_t)M * Hq;          // 8*TH
    bf16_t* hqbf    = hkbf + (size_t)Bq * TH;            // 8*TH
    bf16_t* zbf     = hqbf + (size_t)Bq * TH;            // TH zeros
    bf16_t* featw   = zbf + (size_t)TH;                  // 256x288
    bf16_t* Wk      = featw + 256 * 288;                 // 1024x512
    bf16_t* Wq      = Wk + 1024 * 512;                   // 1024x512
    bf16_t* scw     = Wq + 1024 * 512;                   // 256x256
    bf16_t* enw     = scw + 256 * 256;                   // 256x512
    bf16_t* mkw     = enw + 256 * 512;                   // 384x256

    float* gk = gbuf;
    float* gq = gbuf + (size_t)Tq * Gq;
    float* ck = cst;
    float* cq = cst + TH;

    hipMemsetAsync(cst, 0, (size_t)2 * TH * sizeof(float), stream);
    hipMemsetAsync(zbf, 0, (size_t)TH * sizeof(bf16_t), stream);
    hipMemsetAsync(out1, 0, (size_t)Bq * Tq * Tq * sizeof(float), stream);

    auto cvt = [&](const float* src, bf16_t* dst, int dld, int coff,
                   int rows, int cols, int srows, int scols) {
        f2bf<<<(rows * cols + 255) / 256, 256, 0, stream>>>(src, dst, dld, coff, rows, cols, srows, scols);
    };
    cvt(x,         xbf,   288, 0,   M, 288,     M, Fq);
    cvt(feat_w,    featw, 288, 0, 256, 288,   256, Fq);
    cvt(k_Wih,     Wk,    512, 0,  Gq, Hq,     Gq, Hq);
    cvt(k_Whh,     Wk,    512, Hq, Gq, Hq,     Gq, Hq);
    cvt(q_Wih,     Wq,    512, 0,  Gq, Hq,     Gq, Hq);
    cvt(q_Whh,     Wq,    512, Hq, Gq, Hq,     Gq, Hq);
    cvt(score_w,   scw,   256, 0, 256, 256,   256, 256);
    cvt(enhance_w, enw,   512, 0, 256, 512,   256, 512);
    cvt(mask_w,    mkw,   256, 0, 384, 256,    Fq, 256);

    // 1) feat: hfeatbf = tanh(x @ feat_w^T + feat_b)
    gemm_mfma<1, false, true, false><<<dim3(2, M / 128), 256, 0, stream>>>(
        xbf, 288, 288, nullptr, 0, 0, featw, feat_b, nullptr, 0,
        nullptr, hfeatbf, Hq, 1 << 30);

    // 2) LSTM k & q: 8 steps over axis 0
    for (int b = 0; b < Bq; ++b) {
        const bf16_t* pk = b ? hkbf + (size_t)(b - 1) * TH : zbf;
        const bf16_t* pq = b ? hqbf + (size_t)(b - 1) * TH : zbf;
        lstm_gates_mfma<<<dim3(Gq / 128, Tq / 128, 2), 256, 0, stream>>>(
            hfeatbf + (size_t)b * TH, pk, pq, Wk, Wq, gk, gq);
        lstm_cell<<<dim3(TH / 256, 2), 256, 0, stream>>>(
            gk, gq, k_bih, k_bhh, q_bih, q_bhh, ck, cq,
            hkbf + (size_t)b * TH, hqbf + (size_t)b * TH);
    }

    // 3) score: qsbf = q @ score_w^T  (bf16 out, reuses xbf)
    bf16_t* qsbf = xbf;
    gemm_mfma<0, false, true, false><<<dim3(2, M / 128), 256, 0, stream>>>(
        hqbf, Hq, Hq, nullptr, 0, 0, scw, nullptr, nullptr, 0,
        nullptr, qsbf, Hq, 1 << 30);

    // 4+5) fused banded softmax + PV  (c_att bf16, reuses gbuf)
    bf16_t* c_att = (bf16_t*)gbuf;
    band_fused<<<dim3(Tq / 64, Bq), 256, 0, stream>>>(qsbf, hkbf, out1, c_att);

    // 6) enhance: out_h = tanh([c, q] @ enhance_w^T + b)  (bf16, reuses hfeatbf)
    bf16_t* outh = hfeatbf;
    gemm_mfma<1, false, true, false><<<dim3(2, M / 128), 256, 0, stream>>>(
        c_att, Hq, Hq, hqbf, Hq, Hq, enw, enhance_b, nullptr, 0,
        nullptr, outh, Hq, 1 << 30);

    // 7) mask + final: out0 = x * sigmoid(out_h @ mask_w^T + mask_b)
    gemm_mfma<2, true, false, true><<<dim3(3, M / 128), 256, 0, stream>>>(
        outh, Hq, Hq, nullptr, 0, 0, mkw, mask_b, x, Fq,
        out0, nullptr, Fq, Fq);
}

// Round 4
// 300.612 us; speedup vs baseline: 4.4162x; 1.0715x over previous
//
#include <hip/hip_runtime.h>
#include <math.h>

// ---------------------------------------------------------------------------
// AttentionModel on MI355X. Round 4:
//  - LSTM cell fused into gate-GEMM epilogue (gate-major fragment layout)
//  - band_fused writes the full out1 rows (no 134MB memset dispatch)
//  - all fp32->bf16 conversions batched into one kernel
// ---------------------------------------------------------------------------

#define Bq 8
#define Tq 2048
#define Fq 257
#define Hq 256
#define Gq 1024          // 4*H
#define TH (Tq*Hq)       // 524288
#define KW 192           // k-window rows per 64-row t-tile
#define PLD 40           // P row stride (bf16)
#define KTLD 40          // KT row stride (bf16)
#define Mq (Bq*Tq)       // 16384

typedef __bf16 bf16_t;
typedef __bf16 bf16x8 __attribute__((ext_vector_type(8)));
typedef float f32x4 __attribute__((ext_vector_type(4)));

__device__ __forceinline__ float sigf(float x) { return 1.0f / (1.0f + __expf(-x)); }
__device__ __forceinline__ float tanh_f(float x) { return 1.0f - 2.0f / (__expf(2.0f * x) + 1.0f); }

// ------------------- batched fp32 -> bf16 convert (one dispatch) ------------
#define CV_X   (Mq*288)            // x padded 257->288
#define CV_FW  (256*288)           // feat_w padded
#define CV_WK  (1024*512)          // [k_Wih | k_Whh]
#define CV_WQ  (1024*512)
#define CV_SC  (256*256)
#define CV_EN  (256*512)
#define CV_MK  (384*256)           // mask_w padded rows 257->384
#define CV_O1  CV_X
#define CV_O2  (CV_O1+CV_FW)
#define CV_O3  (CV_O2+CV_WK)
#define CV_O4  (CV_O3+CV_WQ)
#define CV_O5  (CV_O4+CV_SC)
#define CV_O6  (CV_O5+CV_EN)
#define CV_TOT (CV_O6+CV_MK)       // 6,135,808 (divisible by 8*256)

__global__ __launch_bounds__(256) void cvt_all(
    const float* __restrict__ x, const float* __restrict__ feat_w,
    const float* __restrict__ kWih, const float* __restrict__ kWhh,
    const float* __restrict__ qWih, const float* __restrict__ qWhh,
    const float* __restrict__ scorew, const float* __restrict__ enhw,
    const float* __restrict__ maskw, bf16_t* __restrict__ dst)
{
    const int base = (blockIdx.x * 256 + threadIdx.x) * 8;
    if (base >= CV_TOT) return;
    bf16_t v[8];
#pragma unroll
    for (int e = 0; e < 8; ++e) {
        const int i = base + e;
        float f;
        if (i < CV_O1)      { const int r = i / 288, c = i - r * 288;
                              f = (c < Fq) ? x[(size_t)r * Fq + c] : 0.0f; }
        else if (i < CV_O2) { const int i2 = i - CV_O1, r = i2 / 288, c = i2 - r * 288;
                              f = (c < Fq) ? feat_w[r * Fq + c] : 0.0f; }
        else if (i < CV_O3) { const int i2 = i - CV_O2, r = i2 >> 9, c = i2 & 511;
                              f = (c < 256) ? kWih[r * 256 + c] : kWhh[r * 256 + c - 256]; }
        else if (i < CV_O4) { const int i2 = i - CV_O3, r = i2 >> 9, c = i2 & 511;
                              f = (c < 256) ? qWih[r * 256 + c] : qWhh[r * 256 + c - 256]; }
        else if (i < CV_O5) { f = scorew[i - CV_O4]; }
        else if (i < CV_O6) { f = enhw[i - CV_O5]; }
        else                { const int i2 = i - CV_O6, r = i2 >> 8, c = i2 & 255;
                              f = (r < Fq) ? maskw[r * 256 + c] : 0.0f; }
        v[e] = (bf16_t)f;
    }
    *(bf16x8*)(dst + base) = *(bf16x8*)v;
}

// ----------------------------- bf16 MFMA NT GEMM ----------------------------
// 128x128 tile, 4 waves (2x2 of 64x64), BK=32. A split in two K-segments.
template<int ACT, bool MULX, bool BF16OUT, bool F32OUT>
__device__ __forceinline__ void gemm_core(
    const bf16_t* __restrict__ A1, int lda1, int K1,
    const bf16_t* __restrict__ A2, int lda2, int K2,
    const bf16_t* __restrict__ W,
    const float* __restrict__ bias,
    const float* __restrict__ xm, int ldx,
    float* __restrict__ out, bf16_t* __restrict__ outbf, int ldo,
    int Nlog, int m0, int n0)
{
    __shared__ __align__(16) bf16_t As[128 * 32];
    __shared__ __align__(16) bf16_t Ws[128 * 32];
    const int tid = threadIdx.x;
    const int lane = tid & 63;
    const int wave = tid >> 6;
    const int wr = wave >> 1, wc = wave & 1;
    const int fr = lane & 15;
    const int fo = (lane >> 4) * 8;
    const int srow = tid >> 2;
    const int scol = (tid & 3) * 8;

    f32x4 acc[4][4] = {};

    const int K = K1 + K2;
    const int ldw = K;
    for (int k0 = 0; k0 < K; k0 += 32) {
        const bf16_t* Aseg; int kk, lda;
        if (k0 < K1) { Aseg = A1; kk = k0;      lda = lda1; }
        else         { Aseg = A2; kk = k0 - K1; lda = lda2; }
        const uint4 a0 = *(const uint4*)(Aseg + (size_t)(m0 + srow)      * lda + kk + scol);
        const uint4 a1 = *(const uint4*)(Aseg + (size_t)(m0 + srow + 64) * lda + kk + scol);
        const uint4 w0 = *(const uint4*)(W    + (size_t)(n0 + srow)      * ldw + k0 + scol);
        const uint4 w1 = *(const uint4*)(W    + (size_t)(n0 + srow + 64) * ldw + k0 + scol);
        __syncthreads();
        *(uint4*)&As[srow * 32 + scol]        = a0;
        *(uint4*)&As[(srow + 64) * 32 + scol] = a1;
        *(uint4*)&Ws[srow * 32 + scol]        = w0;
        *(uint4*)&Ws[(srow + 64) * 32 + scol] = w1;
        __syncthreads();
        bf16x8 af[4], bfr[4];
#pragma unroll
        for (int i = 0; i < 4; ++i) af[i]  = *(const bf16x8*)&As[(wr * 64 + i * 16 + fr) * 32 + fo];
#pragma unroll
        for (int j = 0; j < 4; ++j) bfr[j] = *(const bf16x8*)&Ws[(wc * 64 + j * 16 + fr) * 32 + fo];
#pragma unroll
        for (int i = 0; i < 4; ++i)
#pragma unroll
            for (int j = 0; j < 4; ++j)
                acc[i][j] = __builtin_amdgcn_mfma_f32_16x16x32_bf16(af[i], bfr[j], acc[i][j], 0, 0, 0);
    }

    const int rbase = (lane >> 4) * 4;
#pragma unroll
    for (int i = 0; i < 4; ++i) {
#pragma unroll
        for (int j = 0; j < 4; ++j) {
            const int n = n0 + wc * 64 + j * 16 + fr;
            if (n >= Nlog) continue;
            const float bv = bias ? bias[n] : 0.0f;
            const int m = m0 + wr * 64 + i * 16 + rbase;
#pragma unroll
            for (int r = 0; r < 4; ++r) {
                float v = acc[i][j][r] + bv;
                if (ACT == 1) v = tanh_f(v);
                else if (ACT == 2) v = sigf(v);
                if (MULX) v *= xm[(size_t)(m + r) * ldx + n];
                if (F32OUT) out[(size_t)(m + r) * ldo + n] = v;
                if (BF16OUT) outbf[(size_t)(m + r) * ldo + n] = (bf16_t)v;
            }
        }
    }
}

template<int ACT, bool MULX, bool BF16OUT, bool F32OUT>
__global__ __launch_bounds__(256) void gemm_mfma(
    const bf16_t* A1, int lda1, int K1, const bf16_t* A2, int lda2, int K2,
    const bf16_t* W, const float* bias, const float* xm, int ldx,
    float* out, bf16_t* outbf, int ldo, int Nlog)
{
    gemm_core<ACT, MULX, BF16OUT, F32OUT>(A1, lda1, K1, A2, lda2, K2, W, bias, xm, ldx,
                                          out, outbf, ldo, Nlog,
                                          blockIdx.y * 128, blockIdx.x * 128);
}

// --------------- fused LSTM step: gate GEMM + cell epilogue ------------------
// Block covers 128 t-rows x 32 j's x 4 gates (gate-major strips of W).
// gates = hx @ Wih^T + hprev @ Whh^T; cell applied in-register; h -> bf16.
__global__ __launch_bounds__(256) void lstm_step(
    const bf16_t* __restrict__ hx,
    const bf16_t* __restrict__ pk, const bf16_t* __restrict__ pq,   // null at b=0
    const bf16_t* __restrict__ Wkw, const bf16_t* __restrict__ Wqw,
    const float* __restrict__ kbih, const float* __restrict__ kbhh,
    const float* __restrict__ qbih, const float* __restrict__ qbhh,
    float* __restrict__ ck, float* __restrict__ cq,
    bf16_t* __restrict__ hk, bf16_t* __restrict__ hq)
{
    __shared__ __align__(16) bf16_t As[128 * 32];
    __shared__ __align__(16) bf16_t Ws[128 * 32];
    const int z = blockIdx.z;
    const bf16_t* hprev = z ? pq : pk;
    const bf16_t* W     = z ? Wqw : Wkw;
    const float* bih    = z ? qbih : kbih;
    const float* bhh    = z ? qbhh : kbhh;
    float* c            = z ? cq : ck;
    bf16_t* hout        = z ? hq : hk;

    const int tid = threadIdx.x, lane = tid & 63, wave = tid >> 6;
    const int wr = wave >> 1, wc = wave & 1;
    const int fr = lane & 15, rg = lane >> 4, fo = rg * 8;
    const int srow = tid >> 2, scol = (tid & 3) * 8;
    const int m0 = blockIdx.y * 128;
    const int jb = blockIdx.x * 32;

    // W staging row s -> global W row (s>>5)*256 + jb + (s&31)  (gate-major strips)
    const int n0 = ((srow      >> 5) * 256) + jb + (srow & 31);
    const int n1 = (((srow+64) >> 5) * 256) + jb + ((srow+64) & 31);

    f32x4 acc[4][4] = {};
    for (int k0 = 0; k0 < 512; k0 += 32) {
        const bf16_t* Aseg; int kk;
        if (k0 < 256) { Aseg = hx;    kk = k0; }
        else          { Aseg = hprev; kk = k0 - 256; }
        uint4 a0 = {0,0,0,0}, a1 = {0,0,0,0};
        if (Aseg) {
            a0 = *(const uint4*)(Aseg + (size_t)(m0 + srow)      * Hq + kk + scol);
            a1 = *(const uint4*)(Aseg + (size_t)(m0 + srow + 64) * Hq + kk + scol);
        }
        const uint4 w0 = *(const uint4*)(W + (size_t)n0 * 512 + k0 + scol);
        const uint4 w1 = *(const uint4*)(W + (size_t)n1 * 512 + k0 + scol);
        __syncthreads();
        *(uint4*)&As[srow * 32 + scol]        = a0;
        *(uint4*)&As[(srow + 64) * 32 + scol] = a1;
        *(uint4*)&Ws[srow * 32 + scol]        = w0;
        *(uint4*)&Ws[(srow + 64) * 32 + scol] = w1;
        __syncthreads();
        bf16x8 af[4], bg[4];
#pragma unroll
        for (int i = 0; i < 4; ++i) af[i] = *(const bf16x8*)&As[(wr * 64 + i * 16 + fr) * 32 + fo];
#pragma unroll
        for (int g = 0; g < 4; ++g) bg[g] = *(const bf16x8*)&Ws[(g * 32 + wc * 16 + fr) * 32 + fo];
#pragma unroll
        for (int i = 0; i < 4; ++i)
#pragma unroll
            for (int g = 0; g < 4; ++g)
                acc[i][g] = __builtin_amdgcn_mfma_f32_16x16x32_bf16(af[i], bg[g], acc[i][g], 0, 0, 0);
    }

    // epilogue: thread owns all 4 gates of column j for 16 rows
    const int j = jb + wc * 16 + fr;
    float bs[4];
#pragma unroll
    for (int g = 0; g < 4; ++g) bs[g] = bih[g * 256 + j] + bhh[g * 256 + j];
#pragma unroll
    for (int i = 0; i < 4; ++i) {
#pragma unroll
        for (int r = 0; r < 4; ++r) {
            const int t = m0 + wr * 64 + i * 16 + rg * 4 + r;
            const size_t ix = (size_t)t * Hq + j;
            const float gi = acc[i][0][r] + bs[0];
            const float gf = acc[i][1][r] + bs[1];
            const float gg = acc[i][2][r] + bs[2];
            const float go = acc[i][3][r] + bs[3];
            const float cn = sigf(gf) * c[ix] + sigf(gi) * tanh_f(gg);
            c[ix] = cn;
            hout[ix] = (bf16_t)(sigf(go) * tanh_f(cn));
        }
    }
}

// ----------------------- fused banded attention -----------------------------
// Per block: batch b, 64 t-rows. K window (192x256) staged in LDS; QK^T MFMA;
// exact in-register band softmax; full out1 rows written (band f32 + zeros);
// PV via MFMA with per-32-j LDS transpose of K.
__global__ __launch_bounds__(256) void band_fused(
    const bf16_t* __restrict__ qsbf, const bf16_t* __restrict__ kbf,
    float* __restrict__ out1, bf16_t* __restrict__ c_att)
{
    __shared__ __align__(16) bf16_t Ks[8 * KW * 32];     // 98304 B, [h/32][j][32]
    __shared__ __align__(16) bf16_t P[6 * 64 * PLD];     // 30720 B
    __shared__ __align__(16) bf16_t KT[256 * KTLD];      // 20480 B

    const int b = blockIdx.y;
    const int t0 = blockIdx.x * 64;
    const int u0 = t0 - 128;
    const int tid = threadIdx.x, lane = tid & 63, w = tid >> 6;
    const int fr = lane & 15, rg = lane >> 4, fo = rg * 8;
    const size_t kbase = (size_t)b * Tq;

    // ---- stage K window rows u0 .. u0+191 (coalesced; zeros for u<0) ----
#pragma unroll
    for (int it = 0; it < 24; ++it) {
        const int idx = it * 256 + tid;
        const int n  = idx >> 5;
        const int c8 = (idx & 31) * 8;
        uint4 v = {0, 0, 0, 0};
        const int u = u0 + n;
        if (u >= 0) v = *(const uint4*)(kbf + (kbase + u) * (size_t)Hq + c8);
        *(uint4*)&Ks[((c8 >> 5) * KW + n) * 32 + (c8 & 31)] = v;
    }
    __syncthreads();

    // ---- QK^T ----
    f32x4 acc[12] = {};
    const bf16_t* qrow = qsbf + (kbase + t0 + 16 * w + fr) * (size_t)Hq;
#pragma unroll
    for (int ks = 0; ks < 8; ++ks) {
        const bf16x8 aq = *(const bf16x8*)(qrow + ks * 32 + fo);
#pragma unroll
        for (int jf = 0; jf < 12; ++jf) {
            const bf16x8 bk = *(const bf16x8*)&Ks[(ks * KW + jf * 16 + fr) * 32 + fo];
            acc[jf] = __builtin_amdgcn_mfma_f32_16x16x32_bf16(aq, bk, acc[jf], 0, 0, 0);
        }
    }

    // ---- band softmax ----
    const int jmin = (128 - t0) > 0 ? (128 - t0) : 0;
    float mx[4] = {-3e38f, -3e38f, -3e38f, -3e38f};
#pragma unroll
    for (int jf = 0; jf < 12; ++jf)
#pragma unroll
        for (int r = 0; r < 4; ++r) {
            const int i = 16 * w + rg * 4 + r;
            const int j = jf * 16 + fr;
            if (j >= i && j <= i + 128 && j >= jmin)
                mx[r] = fmaxf(mx[r], acc[jf][r]);
        }
#pragma unroll
    for (int d = 1; d < 16; d <<= 1)
#pragma unroll
        for (int r = 0; r < 4; ++r) mx[r] = fmaxf(mx[r], __shfl_xor(mx[r], d));

    float ex[12][4];
    float sm[4] = {0.0f, 0.0f, 0.0f, 0.0f};
#pragma unroll
    for (int jf = 0; jf < 12; ++jf)
#pragma unroll
        for (int r = 0; r < 4; ++r) {
            const int i = 16 * w + rg * 4 + r;
            const int j = jf * 16 + fr;
            const bool v = (j >= i && j <= i + 128 && j >= jmin);
            const float e = v ? __expf(acc[jf][r] - mx[r]) : 0.0f;
            ex[jf][r] = e;
            sm[r] += e;
        }
#pragma unroll
    for (int d = 1; d < 16; d <<= 1)
#pragma unroll
        for (int r = 0; r < 4; ++r) sm[r] += __shfl_xor(sm[r], d);
    float inv[4];
#pragma unroll
    for (int r = 0; r < 4; ++r) inv[r] = 1.0f / (sm[r] + 1e-10f);

    // ---- band values -> out1 (f32) + P (bf16 LDS) ----
#pragma unroll
    for (int jf = 0; jf < 12; ++jf)
#pragma unroll
        for (int r = 0; r < 4; ++r) {
            const int i = 16 * w + rg * 4 + r;
            const int j = jf * 16 + fr;
            const float wv = ex[jf][r] * inv[r];
            if (u0 + j >= 0)
                out1[(kbase + t0 + i) * (size_t)Tq + (u0 + j)] = wv;
            P[((j >> 5) * 64 + i) * PLD + (j & 31)] = (bf16_t)wv;
        }

    // ---- zero-fill out1 outside the window (window is float4-aligned) ----
    {
        const int c4l = (u0 > 0 ? u0 : 0) >> 2;   // zeros: [0, c4l)
        const int c4r = (u0 + KW) >> 2;           // zeros: [c4r, 512)
        const float4 z4 = {0.0f, 0.0f, 0.0f, 0.0f};
        for (int rr = 0; rr < 16; ++rr) {
            float* rowp = out1 + (kbase + t0 + 16 * w + rr) * (size_t)Tq;
            for (int c4 = lane; c4 < c4l; c4 += 64)
                *(float4*)(rowp + 4 * c4) = z4;
            for (int c4 = c4r + lane; c4 < Tq / 4; c4 += 64)
                *(float4*)(rowp + 4 * c4) = z4;
        }
    }

    // ---- PV with per-32-j LDS transpose of K ----
    f32x4 cacc[16] = {};
    for (int jc = 0; jc < 6; ++jc) {
        __syncthreads();
#pragma unroll
        for (int it = 0; it < 4; ++it) {
            const int idx = it * 256 + tid;
            const int jl = idx >> 5;
            const int hc = (idx & 31) * 8;
            const bf16x8 kv = *(const bf16x8*)&Ks[((hc >> 5) * KW + jc * 32 + jl) * 32 + (hc & 31)];
#pragma unroll
            for (int e = 0; e < 8; ++e) KT[(hc + e) * KTLD + jl] = kv[e];
        }
        __syncthreads();
        const bf16x8 pa = *(const bf16x8*)&P[(jc * 64 + 16 * w + fr) * PLD + fo];
#pragma unroll
        for (int hf = 0; hf < 16; ++hf) {
            const bf16x8 bk = *(const bf16x8*)&KT[(hf * 16 + fr) * KTLD + fo];
            cacc[hf] = __builtin_amdgcn_mfma_f32_16x16x32_bf16(pa, bk, cacc[hf], 0, 0, 0);
        }
    }

#pragma unroll
    for (int hf = 0; hf < 16; ++hf)
#pragma unroll
        for (int r = 0; r < 4; ++r) {
            const int i = 16 * w + rg * 4 + r;
            c_att[(kbase + t0 + i) * (size_t)Hq + hf * 16 + fr] = (bf16_t)cacc[hf][r];
        }
}

// ---------------------------------------------------------------------------
extern "C" void kernel_launch(void* const* d_in, const int* in_sizes, int n_in,
                              void* d_out, int out_size, void* d_ws, size_t ws_size,
                              hipStream_t stream)
{
    (void)in_sizes; (void)n_in; (void)out_size; (void)ws_size;
    const float* x        = (const float*)d_in[0];
    const float* feat_w   = (const float*)d_in[1];
    const float* feat_b   = (const float*)d_in[2];
    const float* k_Wih    = (const float*)d_in[3];
    const float* k_Whh    = (const float*)d_in[4];
    const float* k_bih    = (const float*)d_in[5];
    const float* k_bhh    = (const float*)d_in[6];
    const float* q_Wih    = (const float*)d_in[7];
    const float* q_Whh    = (const float*)d_in[8];
    const float* q_bih    = (const float*)d_in[9];
    const float* q_bhh    = (const float*)d_in[10];
    const float* score_w  = (const float*)d_in[11];
    const float* enhance_w= (const float*)d_in[12];
    const float* enhance_b= (const float*)d_in[13];
    const float* mask_w   = (const float*)d_in[14];
    const float* mask_b   = (const float*)d_in[15];

    float* out0 = (float*)d_out;                         // (8,2048,257)
    float* out1 = out0 + (size_t)Bq * Tq * Fq;           // (8,2048,2048)

    // ---- workspace ----
    float* cst = (float*)d_ws;                           // 2*TH f32 (c states)
    bf16_t* cvd = (bf16_t*)(cst + (size_t)2 * TH);       // conversion block
    bf16_t* xbf     = cvd;                               // M*288 (reused as qsbf)
    bf16_t* featw   = cvd + CV_O1;
    bf16_t* Wk      = cvd + CV_O2;
    bf16_t* Wq      = cvd + CV_O3;
    bf16_t* scw     = cvd + CV_O4;
    bf16_t* enw     = cvd + CV_O5;
    bf16_t* mkw     = cvd + CV_O6;
    bf16_t* hfeatbf = cvd + CV_TOT;                      // M*256 (reused as out_h)
    bf16_t* hkbf    = hfeatbf + (size_t)Mq * Hq;         // 8*TH
    bf16_t* hqbf    = hkbf + (size_t)Bq * TH;            // 8*TH
    bf16_t* cattb   = hqbf + (size_t)Bq * TH;            // M*256

    float* ck = cst;
    float* cq = cst + TH;

    hipMemsetAsync(cst, 0, (size_t)2 * TH * sizeof(float), stream);

    cvt_all<<<CV_TOT / 8 / 256, 256, 0, stream>>>(
        x, feat_w, k_Wih, k_Whh, q_Wih, q_Whh, score_w, enhance_w, mask_w, cvd);

    // 1) feat: hfeatbf = tanh(x @ feat_w^T + feat_b)
    gemm_mfma<1, false, true, false><<<dim3(2, Mq / 128), 256, 0, stream>>>(
        xbf, 288, 288, nullptr, 0, 0, featw, feat_b, nullptr, 0,
        nullptr, hfeatbf, Hq, 1 << 30);

    // 2) LSTM k & q: 8 fused steps over axis 0
    for (int b = 0; b < Bq; ++b) {
        const bf16_t* pk = b ? hkbf + (size_t)(b - 1) * TH : nullptr;
        const bf16_t* pq = b ? hqbf + (size_t)(b - 1) * TH : nullptr;
        lstm_step<<<dim3(8, Tq / 128, 2), 256, 0, stream>>>(
            hfeatbf + (size_t)b * TH, pk, pq, Wk, Wq,
            k_bih, k_bhh, q_bih, q_bhh, ck, cq,
            hkbf + (size_t)b * TH, hqbf + (size_t)b * TH);
    }

    // 3) score: qsbf = q @ score_w^T  (bf16, reuses xbf)
    bf16_t* qsbf = xbf;
    gemm_mfma<0, false, true, false><<<dim3(2, Mq / 128), 256, 0, stream>>>(
        hqbf, Hq, Hq, nullptr, 0, 0, scw, nullptr, nullptr, 0,
        nullptr, qsbf, Hq, 1 << 30);

    // 4+5) fused banded softmax + PV; writes full out1 rows
    band_fused<<<dim3(Tq / 64, Bq), 256, 0, stream>>>(qsbf, hkbf, out1, cattb);

    // 6) enhance: out_h = tanh([c, q] @ enhance_w^T + b)  (bf16, reuses hfeatbf)
    bf16_t* outh = hfeatbf;
    gemm_mfma<1, false, true, false><<<dim3(2, Mq / 128), 256, 0, stream>>>(
        cattb, Hq, Hq, hqbf, Hq, Hq, enw, enhance_b, nullptr, 0,
        nullptr, outh, Hq, 1 << 30);

    // 7) mask + final: out0 = x * sigmoid(out_h @ mask_w^T + mask_b)
    gemm_mfma<2, true, false, true><<<dim3(3, Mq / 128), 256, 0, stream>>>(
        outh, Hq, Hq, nullptr, 0, 0, mkw, mask_b, x, Fq,
        out0, nullptr, Fq, Fq);
}

// Round 5
// 288.967 us; speedup vs baseline: 4.5942x; 1.0403x over previous
//
#include <hip/hip_runtime.h>
#include <math.h>

// ---------------------------------------------------------------------------
// AttentionModel on MI355X. Round 5:
//  - input projection xp = hfeat @ Wih^T (+biases) hoisted out of the
//    recurrence as one big GEMM (M=16384,N=2048,K=256)
//  - lstm_step: Whh-only (K=256), 64x128 tile, 512 blocks (2/CU),
//    reg-staged pipelined K-loop, cell fused in epilogue
// ---------------------------------------------------------------------------

#define Bq 8
#define Tq 2048
#define Fq 257
#define Hq 256
#define Gq 1024          // 4*H
#define TH (Tq*Hq)       // 524288
#define KW 192           // k-window rows per 64-row t-tile
#define PLD 40           // P row stride (bf16)
#define KTLD 40          // KT row stride (bf16)
#define Mq (Bq*Tq)       // 16384

typedef __bf16 bf16_t;
typedef __bf16 bf16x8 __attribute__((ext_vector_type(8)));
typedef float f32x4 __attribute__((ext_vector_type(4)));

__device__ __forceinline__ float sigf(float x) { return 1.0f / (1.0f + __expf(-x)); }
__device__ __forceinline__ float tanh_f(float x) { return 1.0f - 2.0f / (__expf(2.0f * x) + 1.0f); }

// ------------------- batched fp32 -> bf16 convert (one dispatch) ------------
#define CV_X   (Mq*288)            // x padded 257->288
#define CV_FW  (256*288)           // feat_w padded
#define CV_WIH (2048*256)          // [k_Wih ; q_Wih]
#define CV_WHH (2048*256)          // [k_Whh ; q_Whh]
#define CV_SC  (256*256)
#define CV_EN  (256*512)
#define CV_MK  (384*256)           // mask_w padded rows 257->384
#define CV_O1  CV_X
#define CV_O2  (CV_O1+CV_FW)
#define CV_O3  (CV_O2+CV_WIH)
#define CV_O4  (CV_O3+CV_WHH)
#define CV_O5  (CV_O4+CV_SC)
#define CV_O6  (CV_O5+CV_EN)
#define CV_TOT (CV_O6+CV_MK)       // 6,135,808

__global__ __launch_bounds__(256) void cvt_all(
    const float* __restrict__ x, const float* __restrict__ feat_w,
    const float* __restrict__ kWih, const float* __restrict__ kWhh,
    const float* __restrict__ qWih, const float* __restrict__ qWhh,
    const float* __restrict__ scorew, const float* __restrict__ enhw,
    const float* __restrict__ maskw, bf16_t* __restrict__ dst)
{
    const int base = (blockIdx.x * 256 + threadIdx.x) * 8;
    if (base >= CV_TOT) return;
    bf16_t v[8];
#pragma unroll
    for (int e = 0; e < 8; ++e) {
        const int i = base + e;
        float f;
        if (i < CV_O1)      { const int r = i / 288, c = i - r * 288;
                              f = (c < Fq) ? x[(size_t)r * Fq + c] : 0.0f; }
        else if (i < CV_O2) { const int i2 = i - CV_O1, r = i2 / 288, c = i2 - r * 288;
                              f = (c < Fq) ? feat_w[r * Fq + c] : 0.0f; }
        else if (i < CV_O3) { const int i2 = i - CV_O2, r = i2 >> 8, c = i2 & 255;
                              f = (r < 1024) ? kWih[r * 256 + c] : qWih[(r - 1024) * 256 + c]; }
        else if (i < CV_O4) { const int i2 = i - CV_O3, r = i2 >> 8, c = i2 & 255;
                              f = (r < 1024) ? kWhh[r * 256 + c] : qWhh[(r - 1024) * 256 + c]; }
        else if (i < CV_O5) { f = scorew[i - CV_O4]; }
        else if (i < CV_O6) { f = enhw[i - CV_O5]; }
        else                { const int i2 = i - CV_O6, r = i2 >> 8, c = i2 & 255;
                              f = (r < Fq) ? maskw[r * 256 + c] : 0.0f; }
        v[e] = (bf16_t)f;
    }
    *(bf16x8*)(dst + base) = *(bf16x8*)v;
}

// fold the four LSTM bias vectors into one f32[2048]: [kbih+kbhh ; qbih+qbhh]
__global__ void bias_fold(const float* __restrict__ kbih, const float* __restrict__ kbhh,
                          const float* __restrict__ qbih, const float* __restrict__ qbhh,
                          float* __restrict__ out)
{
    const int i = blockIdx.x * 256 + threadIdx.x;   // 0..2047
    out[i] = (i < 1024) ? kbih[i] + kbhh[i] : qbih[i - 1024] + qbhh[i - 1024];
}

// ----------------------------- bf16 MFMA NT GEMM ----------------------------
// 128x128 tile, 4 waves (2x2 of 64x64), BK=32. A split in two K-segments.
template<int ACT, bool MULX, bool BF16OUT, bool F32OUT>
__device__ __forceinline__ void gemm_core(
    const bf16_t* __restrict__ A1, int lda1, int K1,
    const bf16_t* __restrict__ A2, int lda2, int K2,
    const bf16_t* __restrict__ W,
    const float* __restrict__ bias,
    const float* __restrict__ xm, int ldx,
    float* __restrict__ out, bf16_t* __restrict__ outbf, int ldo,
    int Nlog, int m0, int n0)
{
    __shared__ __align__(16) bf16_t As[128 * 32];
    __shared__ __align__(16) bf16_t Ws[128 * 32];
    const int tid = threadIdx.x;
    const int lane = tid & 63;
    const int wave = tid >> 6;
    const int wr = wave >> 1, wc = wave & 1;
    const int fr = lane & 15;
    const int fo = (lane >> 4) * 8;
    const int srow = tid >> 2;
    const int scol = (tid & 3) * 8;

    f32x4 acc[4][4] = {};

    const int K = K1 + K2;
    const int ldw = K;
    for (int k0 = 0; k0 < K; k0 += 32) {
        const bf16_t* Aseg; int kk, lda;
        if (k0 < K1) { Aseg = A1; kk = k0;      lda = lda1; }
        else         { Aseg = A2; kk = k0 - K1; lda = lda2; }
        const uint4 a0 = *(const uint4*)(Aseg + (size_t)(m0 + srow)      * lda + kk + scol);
        const uint4 a1 = *(const uint4*)(Aseg + (size_t)(m0 + srow + 64) * lda + kk + scol);
        const uint4 w0 = *(const uint4*)(W    + (size_t)(n0 + srow)      * ldw + k0 + scol);
        const uint4 w1 = *(const uint4*)(W    + (size_t)(n0 + srow + 64) * ldw + k0 + scol);
        __syncthreads();
        *(uint4*)&As[srow * 32 + scol]        = a0;
        *(uint4*)&As[(srow + 64) * 32 + scol] = a1;
        *(uint4*)&Ws[srow * 32 + scol]        = w0;
        *(uint4*)&Ws[(srow + 64) * 32 + scol] = w1;
        __syncthreads();
        bf16x8 af[4], bfr[4];
#pragma unroll
        for (int i = 0; i < 4; ++i) af[i]  = *(const bf16x8*)&As[(wr * 64 + i * 16 + fr) * 32 + fo];
#pragma unroll
        for (int j = 0; j < 4; ++j) bfr[j] = *(const bf16x8*)&Ws[(wc * 64 + j * 16 + fr) * 32 + fo];
#pragma unroll
        for (int i = 0; i < 4; ++i)
#pragma unroll
            for (int j = 0; j < 4; ++j)
                acc[i][j] = __builtin_amdgcn_mfma_f32_16x16x32_bf16(af[i], bfr[j], acc[i][j], 0, 0, 0);
    }

    const int rbase = (lane >> 4) * 4;
#pragma unroll
    for (int i = 0; i < 4; ++i) {
#pragma unroll
        for (int j = 0; j < 4; ++j) {
            const int n = n0 + wc * 64 + j * 16 + fr;
            if (n >= Nlog) continue;
            const float bv = bias ? bias[n] : 0.0f;
            const int m = m0 + wr * 64 + i * 16 + rbase;
#pragma unroll
            for (int r = 0; r < 4; ++r) {
                float v = acc[i][j][r] + bv;
                if (ACT == 1) v = tanh_f(v);
                else if (ACT == 2) v = sigf(v);
                if (MULX) v *= xm[(size_t)(m + r) * ldx + n];
                if (F32OUT) out[(size_t)(m + r) * ldo + n] = v;
                if (BF16OUT) outbf[(size_t)(m + r) * ldo + n] = (bf16_t)v;
            }
        }
    }
}

template<int ACT, bool MULX, bool BF16OUT, bool F32OUT>
__global__ __launch_bounds__(256) void gemm_mfma(
    const bf16_t* A1, int lda1, int K1, const bf16_t* A2, int lda2, int K2,
    const bf16_t* W, const float* bias, const float* xm, int ldx,
    float* out, bf16_t* outbf, int ldo, int Nlog)
{
    gemm_core<ACT, MULX, BF16OUT, F32OUT>(A1, lda1, K1, A2, lda2, K2, W, bias, xm, ldx,
                                          out, outbf, ldo, Nlog,
                                          blockIdx.y * 128, blockIdx.x * 128);
}

// --------------- LSTM step: h_prev @ Whh^T + xp, cell fused ------------------
// 64 rows x (32 j x 4 gates) per block; grid (8, 32, 2) = 512 blocks.
// Pipelined K-loop (K=256): reg-stage next iter's loads under current MFMA.
__global__ __launch_bounds__(256) void lstm_step(
    const bf16_t* __restrict__ hkp, const bf16_t* __restrict__ hqp,   // null at b=0
    const bf16_t* __restrict__ Whh_all,                               // 2048x256 [k;q]
    const float* __restrict__ xp_b,                                   // Tq x 2048 (this b)
    float* __restrict__ ck, float* __restrict__ cq,
    bf16_t* __restrict__ hk, bf16_t* __restrict__ hq)
{
    __shared__ __align__(16) bf16_t As[64 * 32];    // 4 KB
    __shared__ __align__(16) bf16_t Ws[128 * 32];   // 8 KB
    const int z = blockIdx.z;
    const bf16_t* hprev = z ? hqp : hkp;
    const bf16_t* Wbase = Whh_all + (size_t)z * 1024 * 256;
    float* c     = z ? cq : ck;
    bf16_t* hout = z ? hq : hk;

    const int tid = threadIdx.x, lane = tid & 63, wave = tid >> 6;
    const int wr = wave >> 1, wc = wave & 1;
    const int fr = lane & 15, rg = lane >> 4, fo = rg * 8;
    const int m0 = blockIdx.y * 64;
    const int jb = blockIdx.x * 32;

    f32x4 acc[2][4] = {};

    if (hprev) {
        const int arow = tid >> 2, acol = (tid & 3) * 8;
        const int s0 = tid >> 2, s1 = s0 + 64;
        const int wn0 = ((s0 >> 5) * 256) + jb + (s0 & 31);
        const int wn1 = ((s1 >> 5) * 256) + jb + (s1 & 31);
        uint4 ar  = *(const uint4*)(hprev + (size_t)(m0 + arow) * Hq + acol);
        uint4 w0r = *(const uint4*)(Wbase + (size_t)wn0 * 256 + acol);
        uint4 w1r = *(const uint4*)(Wbase + (size_t)wn1 * 256 + acol);
#pragma unroll
        for (int t = 0; t < 8; ++t) {
            if (t) __syncthreads();                  // prior LDS reads done
            *(uint4*)&As[arow * 32 + acol] = ar;
            *(uint4*)&Ws[s0 * 32 + acol]   = w0r;
            *(uint4*)&Ws[s1 * 32 + acol]   = w1r;
            if (t < 7) {                              // prefetch next k-slice
                const int k = (t + 1) * 32;
                ar  = *(const uint4*)(hprev + (size_t)(m0 + arow) * Hq + k + acol);
                w0r = *(const uint4*)(Wbase + (size_t)wn0 * 256 + k + acol);
                w1r = *(const uint4*)(Wbase + (size_t)wn1 * 256 + k + acol);
            }
            __syncthreads();
            bf16x8 af[2], bg[4];
#pragma unroll
            for (int i = 0; i < 2; ++i) af[i] = *(const bf16x8*)&As[(wr * 32 + i * 16 + fr) * 32 + fo];
#pragma unroll
            for (int g = 0; g < 4; ++g) bg[g] = *(const bf16x8*)&Ws[(g * 32 + wc * 16 + fr) * 32 + fo];
#pragma unroll
            for (int i = 0; i < 2; ++i)
#pragma unroll
                for (int g = 0; g < 4; ++g)
                    acc[i][g] = __builtin_amdgcn_mfma_f32_16x16x32_bf16(af[i], bg[g], acc[i][g], 0, 0, 0);
        }
    }

    // epilogue: thread owns 4 gates of column j for 8 rows (2 frags x 4)
    const int j = jb + wc * 16 + fr;
#pragma unroll
    for (int i = 0; i < 2; ++i) {
#pragma unroll
        for (int r = 0; r < 4; ++r) {
            const int t = m0 + wr * 32 + i * 16 + rg * 4 + r;
            const float* xpr = xp_b + (size_t)t * 2048 + (size_t)z * 1024;
            const float gi = acc[i][0][r] + xpr[j];
            const float gf = acc[i][1][r] + xpr[256 + j];
            const float gg = acc[i][2][r] + xpr[512 + j];
            const float go = acc[i][3][r] + xpr[768 + j];
            const size_t ix = (size_t)t * Hq + j;
            const float cn = sigf(gf) * c[ix] + sigf(gi) * tanh_f(gg);
            c[ix] = cn;
            hout[ix] = (bf16_t)(sigf(go) * tanh_f(cn));
        }
    }
}

// ----------------------- fused banded attention (unchanged) -----------------
__global__ __launch_bounds__(256) void band_fused(
    const bf16_t* __restrict__ qsbf, const bf16_t* __restrict__ kbf,
    float* __restrict__ out1, bf16_t* __restrict__ c_att)
{
    __shared__ __align__(16) bf16_t Ks[8 * KW * 32];     // 98304 B, [h/32][j][32]
    __shared__ __align__(16) bf16_t P[6 * 64 * PLD];     // 30720 B
    __shared__ __align__(16) bf16_t KT[256 * KTLD];      // 20480 B

    const int b = blockIdx.y;
    const int t0 = blockIdx.x * 64;
    const int u0 = t0 - 128;
    const int tid = threadIdx.x, lane = tid & 63, w = tid >> 6;
    const int fr = lane & 15, rg = lane >> 4, fo = rg * 8;
    const size_t kbase = (size_t)b * Tq;

#pragma unroll
    for (int it = 0; it < 24; ++it) {
        const int idx = it * 256 + tid;
        const int n  = idx >> 5;
        const int c8 = (idx & 31) * 8;
        uint4 v = {0, 0, 0, 0};
        const int u = u0 + n;
        if (u >= 0) v = *(const uint4*)(kbf + (kbase + u) * (size_t)Hq + c8);
        *(uint4*)&Ks[((c8 >> 5) * KW + n) * 32 + (c8 & 31)] = v;
    }
    __syncthreads();

    f32x4 acc[12] = {};
    const bf16_t* qrow = qsbf + (kbase + t0 + 16 * w + fr) * (size_t)Hq;
#pragma unroll
    for (int ks = 0; ks < 8; ++ks) {
        const bf16x8 aq = *(const bf16x8*)(qrow + ks * 32 + fo);
#pragma unroll
        for (int jf = 0; jf < 12; ++jf) {
            const bf16x8 bk = *(const bf16x8*)&Ks[(ks * KW + jf * 16 + fr) * 32 + fo];
            acc[jf] = __builtin_amdgcn_mfma_f32_16x16x32_bf16(aq, bk, acc[jf], 0, 0, 0);
        }
    }

    const int jmin = (128 - t0) > 0 ? (128 - t0) : 0;
    float mx[4] = {-3e38f, -3e38f, -3e38f, -3e38f};
#pragma unroll
    for (int jf = 0; jf < 12; ++jf)
#pragma unroll
        for (int r = 0; r < 4; ++r) {
            const int i = 16 * w + rg * 4 + r;
            const int j = jf * 16 + fr;
            if (j >= i && j <= i + 128 && j >= jmin)
                mx[r] = fmaxf(mx[r], acc[jf][r]);
        }
#pragma unroll
    for (int d = 1; d < 16; d <<= 1)
#pragma unroll
        for (int r = 0; r < 4; ++r) mx[r] = fmaxf(mx[r], __shfl_xor(mx[r], d));

    float ex[12][4];
    float sm[4] = {0.0f, 0.0f, 0.0f, 0.0f};
#pragma unroll
    for (int jf = 0; jf < 12; ++jf)
#pragma unroll
        for (int r = 0; r < 4; ++r) {
            const int i = 16 * w + rg * 4 + r;
            const int j = jf * 16 + fr;
            const bool v = (j >= i && j <= i + 128 && j >= jmin);
            const float e = v ? __expf(acc[jf][r] - mx[r]) : 0.0f;
            ex[jf][r] = e;
            sm[r] += e;
        }
#pragma unroll
    for (int d = 1; d < 16; d <<= 1)
#pragma unroll
        for (int r = 0; r < 4; ++r) sm[r] += __shfl_xor(sm[r], d);
    float inv[4];
#pragma unroll
    for (int r = 0; r < 4; ++r) inv[r] = 1.0f / (sm[r] + 1e-10f);

#pragma unroll
    for (int jf = 0; jf < 12; ++jf)
#pragma unroll
        for (int r = 0; r < 4; ++r) {
            const int i = 16 * w + rg * 4 + r;
            const int j = jf * 16 + fr;
            const float wv = ex[jf][r] * inv[r];
            if (u0 + j >= 0)
                out1[(kbase + t0 + i) * (size_t)Tq + (u0 + j)] = wv;
            P[((j >> 5) * 64 + i) * PLD + (j & 31)] = (bf16_t)wv;
        }

    {
        const int c4l = (u0 > 0 ? u0 : 0) >> 2;
        const int c4r = (u0 + KW) >> 2;
        const float4 z4 = {0.0f, 0.0f, 0.0f, 0.0f};
        for (int rr = 0; rr < 16; ++rr) {
            float* rowp = out1 + (kbase + t0 + 16 * w + rr) * (size_t)Tq;
            for (int c4 = lane; c4 < c4l; c4 += 64)
                *(float4*)(rowp + 4 * c4) = z4;
            for (int c4 = c4r + lane; c4 < Tq / 4; c4 += 64)
                *(float4*)(rowp + 4 * c4) = z4;
        }
    }

    f32x4 cacc[16] = {};
    for (int jc = 0; jc < 6; ++jc) {
        __syncthreads();
#pragma unroll
        for (int it = 0; it < 4; ++it) {
            const int idx = it * 256 + tid;
            const int jl = idx >> 5;
            const int hc = (idx & 31) * 8;
            const bf16x8 kv = *(const bf16x8*)&Ks[((hc >> 5) * KW + jc * 32 + jl) * 32 + (hc & 31)];
#pragma unroll
            for (int e = 0; e < 8; ++e) KT[(hc + e) * KTLD + jl] = kv[e];
        }
        __syncthreads();
        const bf16x8 pa = *(const bf16x8*)&P[(jc * 64 + 16 * w + fr) * PLD + fo];
#pragma unroll
        for (int hf = 0; hf < 16; ++hf) {
            const bf16x8 bk = *(const bf16x8*)&KT[(hf * 16 + fr) * KTLD + fo];
            cacc[hf] = __builtin_amdgcn_mfma_f32_16x16x32_bf16(pa, bk, cacc[hf], 0, 0, 0);
        }
    }

#pragma unroll
    for (int hf = 0; hf < 16; ++hf)
#pragma unroll
        for (int r = 0; r < 4; ++r) {
            const int i = 16 * w + rg * 4 + r;
            c_att[(kbase + t0 + i) * (size_t)Hq + hf * 16 + fr] = (bf16_t)cacc[hf][r];
        }
}

// ---------------------------------------------------------------------------
extern "C" void kernel_launch(void* const* d_in, const int* in_sizes, int n_in,
                              void* d_out, int out_size, void* d_ws, size_t ws_size,
                              hipStream_t stream)
{
    (void)in_sizes; (void)n_in; (void)out_size; (void)ws_size;
    const float* x        = (const float*)d_in[0];
    const float* feat_w   = (const float*)d_in[1];
    const float* feat_b   = (const float*)d_in[2];
    const float* k_Wih    = (const float*)d_in[3];
    const float* k_Whh    = (const float*)d_in[4];
    const float* k_bih    = (const float*)d_in[5];
    const float* k_bhh    = (const float*)d_in[6];
    const float* q_Wih    = (const float*)d_in[7];
    const float* q_Whh    = (const float*)d_in[8];
    const float* q_bih    = (const float*)d_in[9];
    const float* q_bhh    = (const float*)d_in[10];
    const float* score_w  = (const float*)d_in[11];
    const float* enhance_w= (const float*)d_in[12];
    const float* enhance_b= (const float*)d_in[13];
    const float* mask_w   = (const float*)d_in[14];
    const float* mask_b   = (const float*)d_in[15];

    float* out0 = (float*)d_out;                         // (8,2048,257)
    float* out1 = out0 + (size_t)Bq * Tq * Fq;           // (8,2048,2048)

    // ---- workspace ----
    float* cst      = (float*)d_ws;                      // 2*TH f32 (c states)
    float* bias_all = cst + (size_t)2 * TH;              // 2048 f32
    float* xp       = bias_all + 2048;                   // Mq*2048 f32 (134 MB)
    bf16_t* cvd = (bf16_t*)(xp + (size_t)Mq * 2048);
    bf16_t* xbf     = cvd;                               // reused as qsbf later
    bf16_t* featw   = cvd + CV_O1;
    bf16_t* Wih_all = cvd + CV_O2;
    bf16_t* Whh_all = cvd + CV_O3;
    bf16_t* scw     = cvd + CV_O4;
    bf16_t* enw     = cvd + CV_O5;
    bf16_t* mkw     = cvd + CV_O6;
    bf16_t* hfeatbf = cvd + CV_TOT;                      // Mq*256 (reused as out_h)
    bf16_t* hkbf    = hfeatbf + (size_t)Mq * Hq;         // 8*TH
    bf16_t* hqbf    = hkbf + (size_t)Bq * TH;            // 8*TH
    bf16_t* cattb   = hqbf + (size_t)Bq * TH;            // Mq*256

    float* ck = cst;
    float* cq = cst + TH;

    hipMemsetAsync(cst, 0, (size_t)2 * TH * sizeof(float), stream);

    cvt_all<<<CV_TOT / 8 / 256, 256, 0, stream>>>(
        x, feat_w, k_Wih, k_Whh, q_Wih, q_Whh, score_w, enhance_w, mask_w, cvd);
    bias_fold<<<8, 256, 0, stream>>>(k_bih, k_bhh, q_bih, q_bhh, bias_all);

    // 1) feat: hfeatbf = tanh(x @ feat_w^T + feat_b)
    gemm_mfma<1, false, true, false><<<dim3(2, Mq / 128), 256, 0, stream>>>(
        xbf, 288, 288, nullptr, 0, 0, featw, feat_b, nullptr, 0,
        nullptr, hfeatbf, Hq, 1 << 30);

    // 2a) xp = hfeat @ [k_Wih;q_Wih]^T + biases   (one big GEMM, f32 out)
    gemm_mfma<0, false, false, true><<<dim3(16, Mq / 128), 256, 0, stream>>>(
        hfeatbf, Hq, Hq, nullptr, 0, 0, Wih_all, bias_all, nullptr, 0,
        xp, nullptr, 2048, 2048);

    // 2b) 8 recurrence steps (Whh only, K=256)
    for (int b = 0; b < Bq; ++b) {
        const bf16_t* pk = b ? hkbf + (size_t)(b - 1) * TH : nullptr;
        const bf16_t* pq = b ? hqbf + (size_t)(b - 1) * TH : nullptr;
        lstm_step<<<dim3(8, Tq / 64, 2), 256, 0, stream>>>(
            pk, pq, Whh_all, xp + (size_t)b * Tq * 2048, ck, cq,
            hkbf + (size_t)b * TH, hqbf + (size_t)b * TH);
    }

    // 3) score: qsbf = q @ score_w^T  (bf16, reuses xbf)
    bf16_t* qsbf = xbf;
    gemm_mfma<0, false, true, false><<<dim3(2, Mq / 128), 256, 0, stream>>>(
        hqbf, Hq, Hq, nullptr, 0, 0, scw, nullptr, nullptr, 0,
        nullptr, qsbf, Hq, 1 << 30);

    // 4+5) fused banded softmax + PV; writes full out1 rows
    band_fused<<<dim3(Tq / 64, Bq), 256, 0, stream>>>(qsbf, hkbf, out1, cattb);

    // 6) enhance: out_h = tanh([c, q] @ enhance_w^T + b)  (bf16, reuses hfeatbf)
    bf16_t* outh = hfeatbf;
    gemm_mfma<1, false, true, false><<<dim3(2, Mq / 128), 256, 0, stream>>>(
        cattb, Hq, Hq, hqbf, Hq, Hq, enw, enhance_b, nullptr, 0,
        nullptr, outh, Hq, 1 << 30);

    // 7) mask + final: out0 = x * sigmoid(out_h @ mask_w^T + mask_b)
    gemm_mfma<2, true, false, true><<<dim3(3, Mq / 128), 256, 0, stream>>>(
        outh, Hq, Hq, nullptr, 0, 0, mkw, mask_b, x, Fq,
        out0, nullptr, Fq, Fq);
}